// Round 5
// baseline (2544.448 us; speedup 1.0000x reference)
//
#include <hip/hip_runtime.h>
#include <hip/hip_bf16.h>

using bf16 = __hip_bfloat16;
typedef __bf16 bf16x8 __attribute__((ext_vector_type(8)));
typedef __bf16 bf16x4 __attribute__((ext_vector_type(4)));
typedef float f32x4 __attribute__((ext_vector_type(4)));
typedef unsigned short u16x4 __attribute__((ext_vector_type(4)));

#define N_CELLS 3000
#define N_GENES 1000
#define M_NODES 4000
#define NP 3072
#define MP 4096
#define CHMAX 1024   // GEMM1 output-chunk columns

// dual-mode scalar read: inputs are f32 (sniffed) or bf16 (hedge)
__device__ __forceinline__ float rdv(const void* p, size_t i, int isbf) {
    if (isbf) return (float)((const bf16*)p)[i];
    return ((const float*)p)[i];
}

// guarded 4-wide row load from dual-mode matrix (n x n), zero-padded
__device__ __forceinline__ f32x4 load4g(const void* A, int n, int row, int col, int isbf) {
    f32x4 v = {0.f, 0.f, 0.f, 0.f};
    if (row < n) {
        if (col + 3 < n) {
            if (isbf) {
                const u16x4 u = *(const u16x4*)((const unsigned short*)A + (size_t)row * n + col);
                #pragma unroll
                for (int k = 0; k < 4; k++) v[k] = __uint_as_float(((unsigned)u[k]) << 16);
            } else {
                v = *(const f32x4*)((const float*)A + (size_t)row * n + col);
            }
        } else {
            #pragma unroll
            for (int k = 0; k < 4; k++)
                if (col + k < n) v[k] = rdv(A, (size_t)row * n + col + k, isbf);
        }
    }
    return v;
}

__device__ __forceinline__ void async_copy16(const bf16* g, bf16* l) {
    __builtin_amdgcn_global_load_lds((const __attribute__((address_space(1))) void*)g,
                                     (__attribute__((address_space(3))) void*)l,
                                     16, 0, 0);
}

// X ~ U[0,1): as bf16 every word's low16 < 0x3F80 (~100%); as f32 ~25%.
__global__ void sniff_dtype(const unsigned int* __restrict__ X, int* __restrict__ flag)
{
    __shared__ int cnt[4];
    int t = threadIdx.x;
    int c = 0;
    for (int i = t; i < 2048; i += 256)
        if ((X[i] & 0xFFFFu) < 0x3F80u) c++;
    #pragma unroll
    for (int off = 32; off > 0; off >>= 1) c += __shfl_down(c, off);
    if ((t & 63) == 0) cnt[t >> 6] = c;
    __syncthreads();
    if (t == 0) flag[0] = (cnt[0] + cnt[1] + cnt[2] + cnt[3] > 1536) ? 1 : 0;
}

// ---------------------------------------------------------------------------
// NT GEMM, double-buffered async global->LDS staging, optional SPLIT-K:
// C[i,j] = sum_k A[i,k]*B[j,k], 128x128 tile, K%32==0, bf16 in, OutT out.
// gridDim.z = S slices; each block covers K-range [z*K/S, (z+1)*K/S).
// ATOMIC: OutT=float, SCALE_ROW folded into partials, atomicAdd to C
// (zeroed by caller). Atomics are coalesced, land in L2, device-scope.
// RELU_BIAS: C=relu(C+bias[j]) (non-split only). TRANS_OUT: store C[j,i].
// SCALE_ROW: *rowinv[i]. XCD-aware bijective block swizzle (m204).
// ---------------------------------------------------------------------------
template<bool RELU_BIAS, bool TRANS_OUT, bool SCALE_ROW, bool ATOMIC, typename OutT>
__global__ __launch_bounds__(256, 2)
void gemm_nt(const bf16* __restrict__ A, int lda,
             const bf16* __restrict__ B, int ldb,
             const bf16* __restrict__ bias,
             const float* __restrict__ rowinv,
             OutT* __restrict__ C, int ldc,
             int K, int mBound, int nBound)
{
    __shared__ __align__(16) bf16 As[2][128 * 32];
    __shared__ __align__(16) bf16 Bs[2][128 * 32];
    const int tid  = threadIdx.x;
    const int wave = tid >> 6;
    const int lane = tid & 63;

    // bijective XCD swizzle within each z-slice (m204 formula)
    const int nwg  = gridDim.x * gridDim.y;
    const int orig = blockIdx.y * gridDim.x + blockIdx.x;
    const int q = nwg >> 3, rr = nwg & 7;
    const int xcd = orig & 7, idx = orig >> 3;
    const int swz = (xcd < rr ? xcd * (q + 1) : rr * (q + 1) + (xcd - rr) * q) + idx;
    const int i0 = (swz / gridDim.x) * 128;
    const int j0 = (swz % gridDim.x) * 128;

    // split-K slice
    const int kSlice = K / gridDim.z;
    const int kBase  = blockIdx.z * kSlice;
    const int kEnd   = kBase + kSlice;

    // async staging: wave w covers rows [w*32, w*32+32); lane -> (srow, 8-elem k)
    const int srow = lane >> 2;          // 0..15
    const int sk   = (lane & 3) * 8;     // 0,8,16,24
    const bf16* gA0 = A + (size_t)(i0 + wave * 32 + srow) * lda + sk;
    const bf16* gA1 = gA0 + (size_t)16 * lda;
    const bf16* gB0 = B + (size_t)(j0 + wave * 32 + srow) * ldb + sk;
    const bf16* gB1 = gB0 + (size_t)16 * ldb;
    const int loA0 = (wave * 32) * 32;
    const int loA1 = (wave * 32 + 16) * 32;

    const int wm = (wave >> 1) * 64;
    const int wn = (wave & 1) * 64;
    const int fr = lane & 15;
    const int fk = (lane >> 4) * 8;

    f32x4 acc[4][4] = {};

    auto stage = [&](int buf, int kt) {
        async_copy16(gA0 + kt, &As[buf][loA0]);
        async_copy16(gA1 + kt, &As[buf][loA1]);
        async_copy16(gB0 + kt, &Bs[buf][loA0]);
        async_copy16(gB1 + kt, &Bs[buf][loA1]);
    };

    stage(0, kBase);
    __syncthreads();             // prologue drain (once)
    int cur = 0;

    for (int kt = kBase; kt < kEnd; kt += 32) {
        if (kt + 32 < kEnd) stage(cur ^ 1, kt + 32);   // prefetch next tile

        bf16x8 af[4], bfv[4];
        #pragma unroll
        for (int t = 0; t < 4; t++) {
            af[t]  = *(const bf16x8*)&As[cur][(wm + t * 16 + fr) * 32 + fk];
            bfv[t] = *(const bf16x8*)&Bs[cur][(wn + t * 16 + fr) * 32 + fk];
        }
        #pragma unroll
        for (int mt = 0; mt < 4; mt++)
            #pragma unroll
            for (int nt = 0; nt < 4; nt++)
                acc[mt][nt] = __builtin_amdgcn_mfma_f32_16x16x32_bf16(
                    af[mt], bfv[nt], acc[mt][nt], 0, 0, 0);

        __syncthreads();   // prefetch landed; reads done -> safe to flip
        cur ^= 1;
    }

    // C/D mapping: col(n)=lane&15, row(m)=(lane>>4)*4+reg
    const int ci = (lane >> 4) * 4;
    const int cj = lane & 15;
    #pragma unroll
    for (int nt = 0; nt < 4; nt++) {
        const int gj = j0 + wn + nt * 16 + cj;
        if (gj >= nBound) continue;
        float bv = 0.f;
        if (RELU_BIAS) bv = (float)bias[gj];
        #pragma unroll
        for (int mt = 0; mt < 4; mt++) {
            #pragma unroll
            for (int rg = 0; rg < 4; rg++) {
                const int gi = i0 + wm + mt * 16 + ci + rg;
                if (gi < mBound) {
                    float v = acc[mt][nt][rg];
                    if (RELU_BIAS) { v += bv; v = v > 0.f ? v : 0.f; }
                    if (SCALE_ROW) v *= rowinv[gi];
                    if constexpr (ATOMIC) {
                        atomicAdd((float*)&C[(size_t)gi * ldc + gj], v);
                    } else {
                        if (TRANS_OUT) C[(size_t)gj * ldc + gi] = (OutT)v;
                        else           C[(size_t)gi * ldc + gj] = (OutT)v;
                    }
                }
            }
        }
    }
}

// dst (rp x cp) bf16 = src (r x c, dual-mode) zero-padded
__global__ void padcopy(const void* __restrict__ src, int r, int c,
                        bf16* __restrict__ dst, int rp, int cp,
                        const int* __restrict__ flag)
{
    const int isbf = flag[0];
    long idx = (long)blockIdx.x * 256 + threadIdx.x;
    if (idx >= (long)rp * cp) return;
    int i = (int)(idx / cp), j = (int)(idx % cp);
    float v = 0.f;
    if (i < r && j < c) v = rdv(src, (size_t)i * c + j, isbf);
    dst[idx] = (bf16)v;
}

// XT (np x np bf16) = transpose of src (n x n, dual-mode), zero-padded.
__global__ void padcopy_T(const void* __restrict__ src, int n,
                          bf16* __restrict__ dst, int np,
                          const int* __restrict__ flag)
{
    __shared__ float t[32][33];
    const int isbf = flag[0];
    const int tx = threadIdx.x & 31;
    const int ty = threadIdx.x >> 5;     // 0..7
    const int i0 = blockIdx.y * 32;      // output row block (i = src col)
    const int k0 = blockIdx.x * 32;      // output col block (k = src row)
    #pragma unroll
    for (int q = 0; q < 4; q++) {        // stage src[k0+r][i0+tx]
        int k = k0 + ty + q * 8;
        float v = 0.f;
        if (k < n && i0 + tx < n) v = rdv(src, (size_t)k * n + i0 + tx, isbf);
        t[ty + q * 8][tx] = v;
    }
    __syncthreads();
    #pragma unroll
    for (int q = 0; q < 4; q++) {        // write dst[i0+r][k0+tx] = src[k0+tx][i0+r]
        int i = ty + q * 8;
        dst[(size_t)(i0 + i) * np + k0 + tx] = (bf16)t[tx][i];
    }
}

__global__ void zero_f32(float* __restrict__ p, int n)
{
    int i = blockIdx.x * 256 + threadIdx.x;
    if (i < n) p[i] = 0.f;
}

// grid-stride vectorized zero (n4 = count of float4)
__global__ void zero_f32v(f32x4* __restrict__ p, long n4)
{
    long i = (long)blockIdx.x * 256 + threadIdx.x;
    const long str = (long)gridDim.x * 256;
    const f32x4 z = {0.f, 0.f, 0.f, 0.f};
    for (; i < n4; i += str) p[i] = z;
}

// grid-stride vectorized f32 -> bf16 convert (n4 = count of 4-elem groups)
__global__ void f32_to_bf16_v4(const f32x4* __restrict__ src, bf16x4* __restrict__ dst, long n4)
{
    long i = (long)blockIdx.x * 256 + threadIdx.x;
    const long str = (long)gridDim.x * 256;
    for (; i < n4; i += str) {
        f32x4 v = src[i];
        bf16x4 w;
        #pragma unroll
        for (int k = 0; k < 4; k++) w[k] = (__bf16)v[k];
        dst[i] = w;
    }
}

// s[i] += sum_o Zt[o,i]*vt[oBase+o]; r likewise. Zt chunk-local (ld = nPad).
__global__ void scores_accum(const bf16* __restrict__ Zt, int ld,
                             int oBase, int oCount,
                             const void* __restrict__ vt, const void* __restrict__ vr,
                             float* __restrict__ s, float* __restrict__ r,
                             const int* __restrict__ flag)
{
    const int isbf = flag[0];
    const int i = blockIdx.x * 256 + threadIdx.x;
    const int o0 = blockIdx.y * 256;
    int o1 = o0 + 256; if (o1 > oCount) o1 = oCount;
    if (o0 >= o1) return;
    float as = 0.f, ar = 0.f;
    for (int o = o0; o < o1; o++) {
        float z = (float)Zt[(size_t)o * ld + i];
        as += z * rdv(vt, oBase + o, isbf);
        ar += z * rdv(vr, oBase + o, isbf);
    }
    atomicAdd(&s[i], as);
    atomicAdd(&r[i], ar);
}

__global__ void scores_bias(float* __restrict__ s, float* __restrict__ r,
                            const void* __restrict__ vtb, const void* __restrict__ vrb,
                            const int* __restrict__ flag)
{
    const int isbf = flag[0];
    int i = blockIdx.x * 256 + threadIdx.x;
    s[i] += rdv(vtb, 0, isbf);
    r[i] += rdv(vrb, 0, isbf);
}

// ---------------------------------------------------------------------------
// Paired E-pass: block (bi<=bj) computes E tiles (I,J) and (J,I), 64x64 each.
// E[i,j] = exp(sigmoid(A[i,j]*s[j] + A[j,i]*r[i])) for i,j<n else 0.
// ---------------------------------------------------------------------------
__global__ __launch_bounds__(256)
void e_pass_pair(const void* __restrict__ A, int n,
                 const float* __restrict__ s, const float* __restrict__ r,
                 bf16* __restrict__ E, int ldE, float* __restrict__ rowsum,
                 const int* __restrict__ flag)
{
    __shared__ float T1t[64][65];   // T1t[a][b] = A[i0+b][j0+a]
    __shared__ float T2t[64][65];   // T2t[a][b] = A[j0+b][i0+a]
    const int bi = blockIdx.y, bj = blockIdx.x;
    if (bj < bi) return;
    const int isbf = flag[0];
    const int tid = threadIdx.x;
    const int i0 = bi * 64, j0 = bj * 64;
    const int tx = tid & 15;         // col group: 4 consecutive cols
    const int ty = tid >> 4;         // 0..15
    const int c0 = 4 * tx;

    #pragma unroll
    for (int rr = 0; rr < 4; rr++) {
        const int rw = ty + 16 * rr;                       // 0..63
        f32x4 v1 = load4g(A, n, i0 + rw, j0 + c0, isbf);   // region1 row
        f32x4 v2 = load4g(A, n, j0 + rw, i0 + c0, isbf);   // region2 row
        #pragma unroll
        for (int k = 0; k < 4; k++) {
            T1t[c0 + k][rw] = v1[k];
            T2t[c0 + k][rw] = v2[k];
        }
    }
    __syncthreads();

    const float LOG2E = 1.442695041f;

    // ---- tile1: rows I, cols J ----
    {
        const f32x4 s4 = *(const f32x4*)&s[j0 + c0];
        #pragma unroll
        for (int q = 0; q < 4; q++) {
            const int li = ty + 16 * q;
            const int gi = i0 + li;
            const float rv = r[gi];
            const f32x4 a = load4g(A, n, gi, j0 + c0, isbf);
            f32x4 ev;
            float part = 0.f;
            #pragma unroll
            for (int k = 0; k < 4; k++) {
                const float trn = T2t[li][c0 + k];             // A[gj][gi]
                const float x = a[k] * s4[k] + trn * rv;
                const float t = __builtin_amdgcn_exp2f(-x * LOG2E);
                const float sig = __builtin_amdgcn_rcpf(1.f + t);
                float e = __builtin_amdgcn_exp2f(sig * LOG2E);
                const int gj = j0 + c0 + k;
                e = (gi < n && gj < n) ? e : 0.f;
                ev[k] = e;
                part += e;
            }
            bf16x4 w;
            #pragma unroll
            for (int k = 0; k < 4; k++) w[k] = (__bf16)ev[k];
            *(bf16x4*)&E[(size_t)gi * ldE + j0 + c0] = w;
            part += __shfl_down(part, 8, 16);
            part += __shfl_down(part, 4, 16);
            part += __shfl_down(part, 2, 16);
            part += __shfl_down(part, 1, 16);
            if (tx == 0) atomicAdd(&rowsum[gi], part);
        }
    }

    // ---- tile2: rows J, cols I (skip on diagonal) ----
    if (bj > bi) {
        const f32x4 s4 = *(const f32x4*)&s[i0 + c0];
        #pragma unroll
        for (int q = 0; q < 4; q++) {
            const int lr = ty + 16 * q;
            const int gr = j0 + lr;
            const float rv = r[gr];
            const f32x4 a = load4g(A, n, gr, i0 + c0, isbf);
            f32x4 ev;
            float part = 0.f;
            #pragma unroll
            for (int k = 0; k < 4; k++) {
                const float trn = T1t[lr][c0 + k];             // A[gj][gr]
                const float x = a[k] * s4[k] + trn * rv;
                const float t = __builtin_amdgcn_exp2f(-x * LOG2E);
                const float sig = __builtin_amdgcn_rcpf(1.f + t);
                float e = __builtin_amdgcn_exp2f(sig * LOG2E);
                const int gj = i0 + c0 + k;
                e = (gr < n && gj < n) ? e : 0.f;
                ev[k] = e;
                part += e;
            }
            bf16x4 w;
            #pragma unroll
            for (int k = 0; k < 4; k++) w[k] = (__bf16)ev[k];
            *(bf16x4*)&E[(size_t)gr * ldE + i0 + c0] = w;
            part += __shfl_down(part, 8, 16);
            part += __shfl_down(part, 4, 16);
            part += __shfl_down(part, 2, 16);
            part += __shfl_down(part, 1, 16);
            if (tx == 0) atomicAdd(&rowsum[gr], part);
        }
    }
}

// inv over ALL nPad rows; pad rows (rowsum==0) -> 0.
__global__ void finalize_inv(const float* __restrict__ rowsum, float* __restrict__ inv, int nPad)
{
    int i = blockIdx.x * 256 + threadIdx.x;
    if (i < nPad) {
        float v = rowsum[i];
        inv[i] = v > 0.f ? 1.f / v : 0.f;
    }
}

// D (MP x 128): rows m<G from gG[c,m] (dual); rows G..M-1 from H3[m-G,c]; else 0
__global__ void build_D(const void* __restrict__ gG, const bf16* __restrict__ H3,
                        bf16* __restrict__ D, const int* __restrict__ flag)
{
    const int isbf = flag[0];
    int idx = blockIdx.x * 256 + threadIdx.x;
    int m = idx >> 7, c = idx & 127;
    float v = 0.f;
    if (c < 64) {
        if (m < N_GENES)      v = rdv(gG, (size_t)c * N_GENES + m, isbf);
        else if (m < M_NODES) v = (float)H3[(size_t)(m - N_GENES) * 128 + c];
    }
    D[idx] = (bf16)v;
}

extern "C" void kernel_launch(void* const* d_in, const int* in_sizes, int n_in,
                              void* d_out, int out_size, void* d_ws, size_t ws_size,
                              hipStream_t stream)
{
    const void* X     = d_in[0];
    const void* A_enc = d_in[1];
    const void* A_dec = d_in[2];
    const void* gG    = d_in[3];
    const void *W[7], *Wb[7], *vt[7], *vtb[7], *vr[7], *vrb[7];
    for (int l = 0; l < 7; l++) {
        W[l]   = d_in[4 + 6 * l + 0];
        Wb[l]  = d_in[4 + 6 * l + 1];
        vt[l]  = d_in[4 + 6 * l + 2];
        vtb[l] = d_in[4 + 6 * l + 3];
        vr[l]  = d_in[4 + 6 * l + 4];
        vrb[l] = d_in[4 + 6 * l + 5];
    }

    const int fop[7] = {512, 256, 128, 256, 512, 4096, 1024};
    const int fip[7] = {3072, 512, 256, 128, 256, 512, 512};
    const int foR[7] = {512, 256, 64, 256, 512, 4000, 1000};
    const int fiR[7] = {3000, 512, 256, 64, 256, 512, 512};

    // ---- workspace layout (~67 MB), small first ----
    char* ws = (char*)d_ws;
    size_t off = 0;
    auto alloc = [&](size_t bytes) -> void* {
        void* p = ws + off;
        off += (bytes + 255) & ~(size_t)255;
        return p;
    };
    int*   flag = (int*)alloc(256);
    float* sb   = (float*)alloc((size_t)MP * 4);   // sb, rb, rsum contiguous
    float* rb   = (float*)alloc((size_t)MP * 4);
    float* rsum = (float*)alloc((size_t)MP * 4);
    float* rinv = (float*)alloc((size_t)MP * 4);
    bf16* Bp[7];
    for (int l = 0; l < 7; l++) Bp[l] = (bf16*)alloc((size_t)fop[l] * 2);
    bf16* RA = (bf16*)alloc((size_t)NP * 512 * 2);   // H1 -> H3 -> D1
    bf16* RB = (bf16*)alloc((size_t)NP * 256 * 2);   // H2 -> Dd
    bf16* RC = (bf16*)alloc((size_t)MP * 512 * 2);   // D2
    bf16 *H1 = RA, *H3 = RA, *D1 = RA;
    bf16 *H2 = RB, *Dd = RB;
    bf16 *D2 = RC;
    bf16* Wp[7];
    for (int l = 0; l < 7; l++) Wp[l] = (bf16*)alloc((size_t)fop[l] * fip[l] * 2);
    bf16*  ZT = (bf16*)alloc((size_t)CHMAX * MP * 2);   // 8 MB
    float* Hf = (float*)alloc((size_t)MP * 512 * 4);    // 8 MB split-K f32 accum
    bf16*  E  = (bf16*)alloc((size_t)MP * MP * 2);      // 32 MB
    // XT = pad(X^T) as bf16 (NP x NP, 18 MB) aliases E: it is consumed by the
    // layer-0 GEMM1 before e_pass (the first writer of E) runs.
    bf16* XT = E;

    // split-K slice count for a contraction of length Kc: want grid >= ~768
    // blocks; slice >= 256 K-elems; slice a multiple of 32.
    auto pickS = [](int base, int Kc) -> int {
        const int steps = Kc / 32;
        int best = 1;
        for (int S = 1; S <= 16; S++) {
            if (steps % S) continue;
            if (Kc / S < 256) continue;
            if (base * S > 1536) break;
            best = S;
            if (base * S >= 768) break;
        }
        return best;
    };

    // ---- prep ----
    // zero both outputs once (split-K gemm2 atomically accumulates into them)
    {
        long n4 = ((long)M_NODES * M_NODES + (long)M_NODES * N_GENES) / 4;
        zero_f32v<<<2048, 256, 0, stream>>>((f32x4*)d_out, n4);
    }
    sniff_dtype<<<1, 256, 0, stream>>>((const unsigned int*)X, flag);
    for (int l = 0; l < 7; l++) {
        long tot = (long)fop[l] * fip[l];
        padcopy<<<dim3((unsigned)((tot + 255) / 256)), 256, 0, stream>>>(
            W[l], foR[l], fiR[l], Wp[l], fop[l], fip[l], flag);
        padcopy<<<dim3((fop[l] + 255) / 256), 256, 0, stream>>>(
            Wb[l], 1, foR[l], Bp[l], 1, fop[l], flag);
    }
    padcopy_T<<<dim3(NP / 32, NP / 32), 256, 0, stream>>>(X, N_CELLS, XT, NP, flag);

    // HoutB != null: intermediate layer -> split-K accumulates into Hf (f32,
    // ld=nBtot), then converted to bf16 Hout. HoutB == null: output layer ->
    // atomicAdd directly into HoutF (pre-zeroed d_out region), real rows only.
    auto layer = [&](const bf16* Hin, int l, const void* Araw,
                     int nReal, int nPad, bf16* HoutB, float* HoutF,
                     int ldOut, int mB, int nBtot) {
        const int K = fip[l], NO = fop[l];
        const int CH = NO > CHMAX ? CHMAX : NO;
        const int nch = NO / CH;
        auto gemm1 = [&](int c) {
            gemm_nt<true, true, false, false, bf16><<<dim3(CH / 128, nPad / 128), 256, 0, stream>>>(
                Hin, K, Wp[l] + (size_t)c * CH * K, K, Bp[l] + c * CH, nullptr,
                ZT, nPad, K, nPad, CH);
        };
        // pass A: scores (sb, rb, rsum zeroed in one launch — contiguous)
        zero_f32<<<dim3(3 * MP / 256), 256, 0, stream>>>(sb, 3 * MP);
        for (int c = 0; c < nch; c++) {
            gemm1(c);
            int oBase = c * CH;
            int oCnt = foR[l] - oBase;
            if (oCnt > CH) oCnt = CH;
            if (oCnt > 0)
                scores_accum<<<dim3(nPad / 256, 4), 256, 0, stream>>>(
                    ZT, nPad, oBase, oCnt, vt[l], vr[l], sb, rb, flag);
        }
        scores_bias<<<dim3(nPad / 256), 256, 0, stream>>>(sb, rb, vtb[l], vrb[l], flag);
        // full E + row sums (once per layer), paired-tile kernel
        e_pass_pair<<<dim3(nPad / 64, nPad / 64), 256, 0, stream>>>(
            Araw, nReal, sb, rb, E, nPad, rsum, flag);
        finalize_inv<<<dim3(nPad / 256), 256, 0, stream>>>(rsum, rinv, nPad);
        // pass B: split-K gemm2, atomic f32 accumulation.
        // NOTE: contraction length here is nPad (E columns), NOT fip[l].
        float* target;
        int ldT, mAcc;
        if (HoutB) {
            target = Hf; ldT = nBtot; mAcc = nPad;
            zero_f32v<<<2048, 256, 0, stream>>>((f32x4*)Hf, (long)nPad * nBtot / 4);
        } else {
            target = HoutF; ldT = ldOut; mAcc = mB;
        }
        for (int c = 0; c < nch; c++) {
            if (nch > 1) gemm1(c);   // ZT intact when nch==1
            int colBase = c * CH;
            int nB = nBtot - colBase;
            if (nB > CH) nB = CH;
            if (nB <= 0) continue;
            const int bx = CH / 128, by = nPad / 128;
            const int S = pickS(bx * by, nPad);
            gemm_nt<false, false, true, true, float><<<dim3(bx, by, S), 256, 0, stream>>>(
                E, nPad, ZT, nPad, nullptr, rinv,
                target + colBase, ldT, nPad, mAcc, nB);
        }
        if (HoutB)
            f32_to_bf16_v4<<<2048, 256, 0, stream>>>(
                (const f32x4*)Hf, (bf16x4*)HoutB, (long)nPad * nBtot / 4);
    };

    // encoder (H0 = X^T staged as XT by padcopy_T)
    layer(XT,      0, A_enc, N_CELLS, NP, H1, nullptr, 512, NP, 512);
    layer(H1,      1, A_enc, N_CELLS, NP, H2, nullptr, 256, NP, 256);
    layer(H2,      2, A_enc, N_CELLS, NP, H3, nullptr, 128, NP, 128);
    // decoder input D = concat([gG, H3^T], axis=1)^T
    build_D<<<dim3((MP * 128) / 256), 256, 0, stream>>>(gG, H3, Dd, flag);
    layer(Dd, 3, A_dec, M_NODES, MP, D1, nullptr, 256, MP, 256);
    layer(D1, 4, A_dec, M_NODES, MP, D2, nullptr, 512, MP, 512);
    // outputs are float32 (reference dtype), accumulated atomically
    float* outCell = (float*)d_out;
    float* outGene = outCell + (size_t)M_NODES * M_NODES;
    layer(D2, 5, A_dec, M_NODES, MP, nullptr, outCell, 4000, 4000, 4000);
    layer(D2, 6, A_dec, M_NODES, MP, nullptr, outGene, 1000, 4000, 1000);
}

// Round 6
// 1898.460 us; speedup vs baseline: 1.3403x; 1.3403x over previous
//
#include <hip/hip_runtime.h>
#include <hip/hip_bf16.h>

using bf16 = __hip_bfloat16;
typedef __bf16 bf16x8 __attribute__((ext_vector_type(8)));
typedef __bf16 bf16x4 __attribute__((ext_vector_type(4)));
typedef float f32x4 __attribute__((ext_vector_type(4)));
typedef unsigned short u16x4 __attribute__((ext_vector_type(4)));

#define N_CELLS 3000
#define N_GENES 1000
#define M_NODES 4000
#define NP 3072
#define MP 4096

// dual-mode scalar read: inputs are f32 (sniffed) or bf16 (hedge)
__device__ __forceinline__ float rdv(const void* p, size_t i, int isbf) {
    if (isbf) return (float)((const bf16*)p)[i];
    return ((const float*)p)[i];
}

// guarded 4-wide row load from dual-mode matrix (n x n), zero-padded
__device__ __forceinline__ f32x4 load4g(const void* A, int n, int row, int col, int isbf) {
    f32x4 v = {0.f, 0.f, 0.f, 0.f};
    if (row < n) {
        if (col + 3 < n) {
            if (isbf) {
                const u16x4 u = *(const u16x4*)((const unsigned short*)A + (size_t)row * n + col);
                #pragma unroll
                for (int k = 0; k < 4; k++) v[k] = __uint_as_float(((unsigned)u[k]) << 16);
            } else {
                v = *(const f32x4*)((const float*)A + (size_t)row * n + col);
            }
        } else {
            #pragma unroll
            for (int k = 0; k < 4; k++)
                if (col + k < n) v[k] = rdv(A, (size_t)row * n + col + k, isbf);
        }
    }
    return v;
}

__device__ __forceinline__ void async_copy16(const bf16* g, bf16* l) {
    __builtin_amdgcn_global_load_lds((const __attribute__((address_space(1))) void*)g,
                                     (__attribute__((address_space(3))) void*)l,
                                     16, 0, 0);
}

// X ~ U[0,1): as bf16 every word's low16 < 0x3F80 (~100%); as f32 ~25%.
__global__ void sniff_dtype(const unsigned int* __restrict__ X, int* __restrict__ flag)
{
    __shared__ int cnt[4];
    int t = threadIdx.x;
    int c = 0;
    for (int i = t; i < 2048; i += 256)
        if ((X[i] & 0xFFFFu) < 0x3F80u) c++;
    #pragma unroll
    for (int off = 32; off > 0; off >>= 1) c += __shfl_down(c, off);
    if ((t & 63) == 0) cnt[t >> 6] = c;
    __syncthreads();
    if (t == 0) flag[0] = (cnt[0] + cnt[1] + cnt[2] + cnt[3] > 1536) ? 1 : 0;
}

// ---------------------------------------------------------------------------
// NT GEMM, double-buffered async global->LDS staging, optional SPLIT-K:
// C[i,j] = sum_k A[i,k]*B[j,k], 128x128 tile, K%32==0, bf16 in, OutT out.
// gridDim.z = S slices; each block covers K-range [z*K/S, (z+1)*K/S).
// ATOMIC: OutT=float, SCALE_ROW folded into partials, atomicAdd to C
// (zeroed by caller). RELU_BIAS: C=relu(C+bias[j]). TRANS_OUT: store C[j,i].
// SCALE_ROW: *rowinv[i]. XCD-aware bijective block swizzle (m204).
// ---------------------------------------------------------------------------
template<bool RELU_BIAS, bool TRANS_OUT, bool SCALE_ROW, bool ATOMIC, typename OutT>
__global__ __launch_bounds__(256, 2)
void gemm_nt(const bf16* __restrict__ A, int lda,
             const bf16* __restrict__ B, int ldb,
             const bf16* __restrict__ bias,
             const float* __restrict__ rowinv,
             OutT* __restrict__ C, int ldc,
             int K, int mBound, int nBound)
{
    __shared__ __align__(16) bf16 As[2][128 * 32];
    __shared__ __align__(16) bf16 Bs[2][128 * 32];
    const int tid  = threadIdx.x;
    const int wave = tid >> 6;
    const int lane = tid & 63;

    // bijective XCD swizzle within each z-slice (m204 formula)
    const int nwg  = gridDim.x * gridDim.y;
    const int orig = blockIdx.y * gridDim.x + blockIdx.x;
    const int q = nwg >> 3, rr = nwg & 7;
    const int xcd = orig & 7, idx = orig >> 3;
    const int swz = (xcd < rr ? xcd * (q + 1) : rr * (q + 1) + (xcd - rr) * q) + idx;
    const int i0 = (swz / gridDim.x) * 128;
    const int j0 = (swz % gridDim.x) * 128;

    // split-K slice
    const int kSlice = K / gridDim.z;
    const int kBase  = blockIdx.z * kSlice;
    const int kEnd   = kBase + kSlice;

    // async staging: wave w covers rows [w*32, w*32+32); lane -> (srow, 8-elem k)
    const int srow = lane >> 2;          // 0..15
    const int sk   = (lane & 3) * 8;     // 0,8,16,24
    const bf16* gA0 = A + (size_t)(i0 + wave * 32 + srow) * lda + sk;
    const bf16* gA1 = gA0 + (size_t)16 * lda;
    const bf16* gB0 = B + (size_t)(j0 + wave * 32 + srow) * ldb + sk;
    const bf16* gB1 = gB0 + (size_t)16 * ldb;
    const int loA0 = (wave * 32) * 32;
    const int loA1 = (wave * 32 + 16) * 32;

    const int wm = (wave >> 1) * 64;
    const int wn = (wave & 1) * 64;
    const int fr = lane & 15;
    const int fk = (lane >> 4) * 8;

    f32x4 acc[4][4] = {};

    auto stage = [&](int buf, int kt) {
        async_copy16(gA0 + kt, &As[buf][loA0]);
        async_copy16(gA1 + kt, &As[buf][loA1]);
        async_copy16(gB0 + kt, &Bs[buf][loA0]);
        async_copy16(gB1 + kt, &Bs[buf][loA1]);
    };

    stage(0, kBase);
    __syncthreads();             // prologue drain (once)
    int cur = 0;

    for (int kt = kBase; kt < kEnd; kt += 32) {
        if (kt + 32 < kEnd) stage(cur ^ 1, kt + 32);   // prefetch next tile

        bf16x8 af[4], bfv[4];
        #pragma unroll
        for (int t = 0; t < 4; t++) {
            af[t]  = *(const bf16x8*)&As[cur][(wm + t * 16 + fr) * 32 + fk];
            bfv[t] = *(const bf16x8*)&Bs[cur][(wn + t * 16 + fr) * 32 + fk];
        }
        #pragma unroll
        for (int mt = 0; mt < 4; mt++)
            #pragma unroll
            for (int nt = 0; nt < 4; nt++)
                acc[mt][nt] = __builtin_amdgcn_mfma_f32_16x16x32_bf16(
                    af[mt], bfv[nt], acc[mt][nt], 0, 0, 0);

        __syncthreads();   // prefetch landed; reads done -> safe to flip
        cur ^= 1;
    }

    // C/D mapping: col(n)=lane&15, row(m)=(lane>>4)*4+reg
    const int ci = (lane >> 4) * 4;
    const int cj = lane & 15;
    #pragma unroll
    for (int nt = 0; nt < 4; nt++) {
        const int gj = j0 + wn + nt * 16 + cj;
        if (gj >= nBound) continue;
        float bv = 0.f;
        if (RELU_BIAS) bv = (float)bias[gj];
        #pragma unroll
        for (int mt = 0; mt < 4; mt++) {
            #pragma unroll
            for (int rg = 0; rg < 4; rg++) {
                const int gi = i0 + wm + mt * 16 + ci + rg;
                if (gi < mBound) {
                    float v = acc[mt][nt][rg];
                    if (RELU_BIAS) { v += bv; v = v > 0.f ? v : 0.f; }
                    if (SCALE_ROW) v *= rowinv[gi];
                    if constexpr (ATOMIC) {
                        atomicAdd((float*)&C[(size_t)gi * ldc + gj], v);
                    } else {
                        if (TRANS_OUT) C[(size_t)gj * ldc + gi] = (OutT)v;
                        else           C[(size_t)gi * ldc + gj] = (OutT)v;
                    }
                }
            }
        }
    }
}

// dst (rp x cp) bf16 = src (r x c, dual-mode) zero-padded
__global__ void padcopy(const void* __restrict__ src, int r, int c,
                        bf16* __restrict__ dst, int rp, int cp,
                        const int* __restrict__ flag)
{
    const int isbf = flag[0];
    long idx = (long)blockIdx.x * 256 + threadIdx.x;
    if (idx >= (long)rp * cp) return;
    int i = (int)(idx / cp), j = (int)(idx % cp);
    float v = 0.f;
    if (i < r && j < c) v = rdv(src, (size_t)i * c + j, isbf);
    dst[idx] = (bf16)v;
}

// XT (np x np bf16) = transpose of src (n x n, dual-mode), zero-padded.
__global__ void padcopy_T(const void* __restrict__ src, int n,
                          bf16* __restrict__ dst, int np,
                          const int* __restrict__ flag)
{
    __shared__ float t[32][33];
    const int isbf = flag[0];
    const int tx = threadIdx.x & 31;
    const int ty = threadIdx.x >> 5;     // 0..7
    const int i0 = blockIdx.y * 32;      // output row block (i = src col)
    const int k0 = blockIdx.x * 32;      // output col block (k = src row)
    #pragma unroll
    for (int q = 0; q < 4; q++) {        // stage src[k0+r][i0+tx]
        int k = k0 + ty + q * 8;
        float v = 0.f;
        if (k < n && i0 + tx < n) v = rdv(src, (size_t)k * n + i0 + tx, isbf);
        t[ty + q * 8][tx] = v;
    }
    __syncthreads();
    #pragma unroll
    for (int q = 0; q < 4; q++) {        // write dst[i0+r][k0+tx] = src[k0+tx][i0+r]
        int i = ty + q * 8;
        dst[(size_t)(i0 + i) * np + k0 + tx] = (bf16)t[tx][i];
    }
}

__global__ void zero_f32(float* __restrict__ p, int n)
{
    int i = blockIdx.x * 256 + threadIdx.x;
    if (i < n) p[i] = 0.f;
}

// grid-stride vectorized zero (n4 = count of float4)
__global__ void zero_f32v(f32x4* __restrict__ p, long n4)
{
    long i = (long)blockIdx.x * 256 + threadIdx.x;
    const long str = (long)gridDim.x * 256;
    const f32x4 z = {0.f, 0.f, 0.f, 0.f};
    for (; i < n4; i += str) p[i] = z;
}

// grid-stride vectorized f32 -> bf16 convert (n4 = count of 4-elem groups)
__global__ void f32_to_bf16_v4(const f32x4* __restrict__ src, bf16x4* __restrict__ dst, long n4)
{
    long i = (long)blockIdx.x * 256 + threadIdx.x;
    const long str = (long)gridDim.x * 256;
    for (; i < n4; i += str) {
        f32x4 v = src[i];
        bf16x4 w;
        #pragma unroll
        for (int k = 0; k < 4; k++) w[k] = (__bf16)v[k];
        dst[i] = w;
    }
}

// s[i] += sum_o Zt[o,i]*vt[oBase+o]; r likewise. Zt chunk-local (ld = nPad).
__global__ void scores_accum(const bf16* __restrict__ Zt, int ld,
                             int oBase, int oCount,
                             const void* __restrict__ vt, const void* __restrict__ vr,
                             float* __restrict__ s, float* __restrict__ r,
                             const int* __restrict__ flag)
{
    const int isbf = flag[0];
    const int i = blockIdx.x * 256 + threadIdx.x;
    const int o0 = blockIdx.y * 256;
    int o1 = o0 + 256; if (o1 > oCount) o1 = oCount;
    if (o0 >= o1) return;
    float as = 0.f, ar = 0.f;
    for (int o = o0; o < o1; o++) {
        float z = (float)Zt[(size_t)o * ld + i];
        as += z * rdv(vt, oBase + o, isbf);
        ar += z * rdv(vr, oBase + o, isbf);
    }
    atomicAdd(&s[i], as);
    atomicAdd(&r[i], ar);
}

__global__ void scores_bias(float* __restrict__ s, float* __restrict__ r,
                            const void* __restrict__ vtb, const void* __restrict__ vrb,
                            const int* __restrict__ flag)
{
    const int isbf = flag[0];
    int i = blockIdx.x * 256 + threadIdx.x;
    s[i] += rdv(vtb, 0, isbf);
    r[i] += rdv(vrb, 0, isbf);
}

// ---------------------------------------------------------------------------
// Paired E-pass: block (bi<=bj) computes E tiles (I,J) and (J,I), 64x64 each.
// E[i,j] = exp(sigmoid(A[i,j]*s[j] + A[j,i]*r[i])) for i,j<n else 0.
// ---------------------------------------------------------------------------
__global__ __launch_bounds__(256)
void e_pass_pair(const void* __restrict__ A, int n,
                 const float* __restrict__ s, const float* __restrict__ r,
                 bf16* __restrict__ E, int ldE, float* __restrict__ rowsum,
                 const int* __restrict__ flag)
{
    __shared__ float T1t[64][65];   // T1t[a][b] = A[i0+b][j0+a]
    __shared__ float T2t[64][65];   // T2t[a][b] = A[j0+b][i0+a]
    const int bi = blockIdx.y, bj = blockIdx.x;
    if (bj < bi) return;
    const int isbf = flag[0];
    const int tid = threadIdx.x;
    const int i0 = bi * 64, j0 = bj * 64;
    const int tx = tid & 15;         // col group: 4 consecutive cols
    const int ty = tid >> 4;         // 0..15
    const int c0 = 4 * tx;

    #pragma unroll
    for (int rr = 0; rr < 4; rr++) {
        const int rw = ty + 16 * rr;                       // 0..63
        f32x4 v1 = load4g(A, n, i0 + rw, j0 + c0, isbf);   // region1 row
        f32x4 v2 = load4g(A, n, j0 + rw, i0 + c0, isbf);   // region2 row
        #pragma unroll
        for (int k = 0; k < 4; k++) {
            T1t[c0 + k][rw] = v1[k];
            T2t[c0 + k][rw] = v2[k];
        }
    }
    __syncthreads();

    const float LOG2E = 1.442695041f;

    // ---- tile1: rows I, cols J ----
    {
        const f32x4 s4 = *(const f32x4*)&s[j0 + c0];
        #pragma unroll
        for (int q = 0; q < 4; q++) {
            const int li = ty + 16 * q;
            const int gi = i0 + li;
            const float rv = r[gi];
            const f32x4 a = load4g(A, n, gi, j0 + c0, isbf);
            f32x4 ev;
            float part = 0.f;
            #pragma unroll
            for (int k = 0; k < 4; k++) {
                const float trn = T2t[li][c0 + k];             // A[gj][gi]
                const float x = a[k] * s4[k] + trn * rv;
                const float t = __builtin_amdgcn_exp2f(-x * LOG2E);
                const float sig = __builtin_amdgcn_rcpf(1.f + t);
                float e = __builtin_amdgcn_exp2f(sig * LOG2E);
                const int gj = j0 + c0 + k;
                e = (gi < n && gj < n) ? e : 0.f;
                ev[k] = e;
                part += e;
            }
            bf16x4 w;
            #pragma unroll
            for (int k = 0; k < 4; k++) w[k] = (__bf16)ev[k];
            *(bf16x4*)&E[(size_t)gi * ldE + j0 + c0] = w;
            part += __shfl_down(part, 8, 16);
            part += __shfl_down(part, 4, 16);
            part += __shfl_down(part, 2, 16);
            part += __shfl_down(part, 1, 16);
            if (tx == 0) atomicAdd(&rowsum[gi], part);
        }
    }

    // ---- tile2: rows J, cols I (skip on diagonal) ----
    if (bj > bi) {
        const f32x4 s4 = *(const f32x4*)&s[i0 + c0];
        #pragma unroll
        for (int q = 0; q < 4; q++) {
            const int lr = ty + 16 * q;
            const int gr = j0 + lr;
            const float rv = r[gr];
            const f32x4 a = load4g(A, n, gr, i0 + c0, isbf);
            f32x4 ev;
            float part = 0.f;
            #pragma unroll
            for (int k = 0; k < 4; k++) {
                const float trn = T1t[lr][c0 + k];             // A[gj][gr]
                const float x = a[k] * s4[k] + trn * rv;
                const float t = __builtin_amdgcn_exp2f(-x * LOG2E);
                const float sig = __builtin_amdgcn_rcpf(1.f + t);
                float e = __builtin_amdgcn_exp2f(sig * LOG2E);
                const int gj = i0 + c0 + k;
                e = (gr < n && gj < n) ? e : 0.f;
                ev[k] = e;
                part += e;
            }
            bf16x4 w;
            #pragma unroll
            for (int k = 0; k < 4; k++) w[k] = (__bf16)ev[k];
            *(bf16x4*)&E[(size_t)gr * ldE + i0 + c0] = w;
            part += __shfl_down(part, 8, 16);
            part += __shfl_down(part, 4, 16);
            part += __shfl_down(part, 2, 16);
            part += __shfl_down(part, 1, 16);
            if (tx == 0) atomicAdd(&rowsum[gr], part);
        }
    }
}

// inv over ALL nPad rows; pad rows (rowsum==0) -> 0.
__global__ void finalize_inv(const float* __restrict__ rowsum, float* __restrict__ inv, int nPad)
{
    int i = blockIdx.x * 256 + threadIdx.x;
    if (i < nPad) {
        float v = rowsum[i];
        inv[i] = v > 0.f ? 1.f / v : 0.f;
    }
}

// D (MP x 128): rows m<G from gG[c,m] (dual); rows G..M-1 from H3[m-G,c]; else 0
__global__ void build_D(const void* __restrict__ gG, const bf16* __restrict__ H3,
                        bf16* __restrict__ D, const int* __restrict__ flag)
{
    const int isbf = flag[0];
    int idx = blockIdx.x * 256 + threadIdx.x;
    int m = idx >> 7, c = idx & 127;
    float v = 0.f;
    if (c < 64) {
        if (m < N_GENES)      v = rdv(gG, (size_t)c * N_GENES + m, isbf);
        else if (m < M_NODES) v = (float)H3[(size_t)(m - N_GENES) * 128 + c];
    }
    D[idx] = (bf16)v;
}

extern "C" void kernel_launch(void* const* d_in, const int* in_sizes, int n_in,
                              void* d_out, int out_size, void* d_ws, size_t ws_size,
                              hipStream_t stream)
{
    const void* X     = d_in[0];
    const void* A_enc = d_in[1];
    const void* A_dec = d_in[2];
    const void* gG    = d_in[3];
    const void *W[7], *Wb[7], *vt[7], *vtb[7], *vr[7], *vrb[7];
    for (int l = 0; l < 7; l++) {
        W[l]   = d_in[4 + 6 * l + 0];
        Wb[l]  = d_in[4 + 6 * l + 1];
        vt[l]  = d_in[4 + 6 * l + 2];
        vtb[l] = d_in[4 + 6 * l + 3];
        vr[l]  = d_in[4 + 6 * l + 4];
        vrb[l] = d_in[4 + 6 * l + 5];
    }

    const int fop[7] = {512, 256, 128, 256, 512, 4096, 1024};
    const int fip[7] = {3072, 512, 256, 128, 256, 512, 512};
    const int foR[7] = {512, 256, 64, 256, 512, 4000, 1000};
    const int fiR[7] = {3000, 512, 256, 64, 256, 512, 512};

    // ZT capacity: full-Z (4096 cols, 32 MB) lets d3's GEMM2 run as ONE
    // 4096^3 dispatch (grid 1024, m97 shape). Fixed allocations ~61 MB, so
    // full-Z needs ~93 MB total; gate on ws_size with margin, else fall back
    // to the verified 1024-col chunked path.
    const int CHcap = (ws_size >= (size_t)100 * 1024 * 1024) ? 4096 : 1024;

    // ---- workspace layout, small first ----
    char* ws = (char*)d_ws;
    size_t off = 0;
    auto alloc = [&](size_t bytes) -> void* {
        void* p = ws + off;
        off += (bytes + 255) & ~(size_t)255;
        return p;
    };
    int*   flag = (int*)alloc(256);
    float* sb   = (float*)alloc((size_t)MP * 4);   // sb, rb, rsum contiguous
    float* rb   = (float*)alloc((size_t)MP * 4);
    float* rsum = (float*)alloc((size_t)MP * 4);
    float* rinv = (float*)alloc((size_t)MP * 4);
    bf16* Bp[7];
    for (int l = 0; l < 7; l++) Bp[l] = (bf16*)alloc((size_t)fop[l] * 2);
    bf16* RA = (bf16*)alloc((size_t)NP * 512 * 2);   // H1 -> H3 -> D1
    bf16* RB = (bf16*)alloc((size_t)NP * 256 * 2);   // H2 -> Dd
    bf16* RC = (bf16*)alloc((size_t)MP * 512 * 2);   // D2
    bf16 *H1 = RA, *H3 = RA, *D1 = RA;
    bf16 *H2 = RB, *Dd = RB;
    bf16 *D2 = RC;
    bf16* Wp[7];
    for (int l = 0; l < 7; l++) Wp[l] = (bf16*)alloc((size_t)fop[l] * fip[l] * 2);
    float* Hf = (float*)alloc((size_t)MP * 512 * 4);        // 8 MB split-K f32 accum
    bf16*  ZT = (bf16*)alloc((size_t)CHcap * MP * 2);       // 8 or 32 MB
    bf16*  E  = (bf16*)alloc((size_t)MP * MP * 2);          // 32 MB
    // XT = pad(X^T) as bf16 (NP x NP, 18 MB) aliases E: it is consumed by the
    // layer-0 GEMM1 before e_pass (the first writer of E) runs.
    bf16* XT = E;

    // split-K slice count for contraction length Kc: only for small grids
    // (base < 192 blocks); want grid >= ~768; slice >= 256 K-elems.
    auto pickS = [](int base, int Kc) -> int {
        if (base >= 192) return 1;
        const int steps = Kc / 32;
        int best = 1;
        for (int S = 1; S <= 16; S++) {
            if (steps % S) continue;
            if (Kc / S < 256) continue;
            if (base * S > 1536) break;
            best = S;
            if (base * S >= 768) break;
        }
        return best;
    };

    // ---- prep ----
    sniff_dtype<<<1, 256, 0, stream>>>((const unsigned int*)X, flag);
    for (int l = 0; l < 7; l++) {
        long tot = (long)fop[l] * fip[l];
        padcopy<<<dim3((unsigned)((tot + 255) / 256)), 256, 0, stream>>>(
            W[l], foR[l], fiR[l], Wp[l], fop[l], fip[l], flag);
        padcopy<<<dim3((fop[l] + 255) / 256), 256, 0, stream>>>(
            Wb[l], 1, foR[l], Bp[l], 1, fop[l], flag);
    }
    padcopy_T<<<dim3(NP / 32, NP / 32), 256, 0, stream>>>(X, N_CELLS, XT, NP, flag);

    // HoutB != null: intermediate layer -> split-K accumulates into Hf (f32,
    // ld=nBtot), then converted to bf16 Hout. HoutB == null: output layer ->
    // direct (non-atomic) f32 store into HoutF, real rows/cols only.
    auto layer = [&](const bf16* Hin, int l, const void* Araw,
                     int nReal, int nPad, bf16* HoutB, float* HoutF,
                     int ldOut, int mB, int nBtot) {
        const int K = fip[l], NO = fop[l];
        const int CH = NO > CHcap ? CHcap : NO;
        const int nch = NO / CH;
        auto gemm1 = [&](int c) {
            gemm_nt<true, true, false, false, bf16><<<dim3(CH / 128, nPad / 128), 256, 0, stream>>>(
                Hin, K, Wp[l] + (size_t)c * CH * K, K, Bp[l] + c * CH, nullptr,
                ZT, nPad, K, nPad, CH);
        };
        // pass A: scores (sb, rb, rsum zeroed in one launch — contiguous)
        zero_f32<<<dim3(3 * MP / 256), 256, 0, stream>>>(sb, 3 * MP);
        for (int c = 0; c < nch; c++) {
            gemm1(c);
            int oBase = c * CH;
            int oCnt = foR[l] - oBase;
            if (oCnt > CH) oCnt = CH;
            if (oCnt > 0)
                scores_accum<<<dim3(nPad / 256, (unsigned)((oCnt + 255) / 256)), 256, 0, stream>>>(
                    ZT, nPad, oBase, oCnt, vt[l], vr[l], sb, rb, flag);
        }
        scores_bias<<<dim3(nPad / 256), 256, 0, stream>>>(sb, rb, vtb[l], vrb[l], flag);
        // full E + row sums (once per layer), paired-tile kernel
        e_pass_pair<<<dim3(nPad / 64, nPad / 64), 256, 0, stream>>>(
            Araw, nReal, sb, rb, E, nPad, rsum, flag);
        finalize_inv<<<dim3(nPad / 256), 256, 0, stream>>>(rsum, rinv, nPad);
        // pass B: gemm2 (contraction length = nPad, the E columns).
        if (HoutB)
            zero_f32v<<<2048, 256, 0, stream>>>((f32x4*)Hf, (long)nPad * nBtot / 4);
        for (int c = 0; c < nch; c++) {
            if (nch > 1) gemm1(c);   // ZT intact when nch==1
            int colBase = c * CH;
            int nB = nBtot - colBase;
            if (nB > CH) nB = CH;
            if (nB <= 0) continue;
            const int bx = CH / 128, by = nPad / 128;
            if (HoutB) {
                const int S = pickS(bx * by, nPad);
                gemm_nt<false, false, true, true, float><<<dim3(bx, by, S), 256, 0, stream>>>(
                    E, nPad, ZT, nPad, nullptr, rinv,
                    Hf + colBase, nBtot, nPad, nPad, nB);
            } else {
                gemm_nt<false, false, true, false, float><<<dim3(bx, by), 256, 0, stream>>>(
                    E, nPad, ZT, nPad, nullptr, rinv,
                    HoutF + colBase, ldOut, nPad, mB, nB);
            }
        }
        if (HoutB)
            f32_to_bf16_v4<<<2048, 256, 0, stream>>>(
                (const f32x4*)Hf, (bf16x4*)HoutB, (long)nPad * nBtot / 4);
    };

    // encoder (H0 = X^T staged as XT by padcopy_T)
    layer(XT,      0, A_enc, N_CELLS, NP, H1, nullptr, 512, NP, 512);
    layer(H1,      1, A_enc, N_CELLS, NP, H2, nullptr, 256, NP, 256);
    layer(H2,      2, A_enc, N_CELLS, NP, H3, nullptr, 128, NP, 128);
    // decoder input D = concat([gG, H3^T], axis=1)^T
    build_D<<<dim3((MP * 128) / 256), 256, 0, stream>>>(gG, H3, Dd, flag);
    layer(Dd, 3, A_dec, M_NODES, MP, D1, nullptr, 256, MP, 256);
    layer(D1, 4, A_dec, M_NODES, MP, D2, nullptr, 512, MP, 512);
    // outputs are float32 (reference dtype), direct stores
    float* outCell = (float*)d_out;
    float* outGene = outCell + (size_t)M_NODES * M_NODES;
    layer(D2, 5, A_dec, M_NODES, MP, nullptr, outCell, 4000, 4000, 4000);
    layer(D2, 6, A_dec, M_NODES, MP, nullptr, outGene, 1000, 4000, 1000);
}

// Round 7
// 1800.824 us; speedup vs baseline: 1.4129x; 1.0542x over previous
//
#include <hip/hip_runtime.h>
#include <hip/hip_bf16.h>

using bf16 = __hip_bfloat16;
typedef __bf16 bf16x8 __attribute__((ext_vector_type(8)));
typedef __bf16 bf16x4 __attribute__((ext_vector_type(4)));
typedef float f32x4 __attribute__((ext_vector_type(4)));
typedef unsigned short u16x4 __attribute__((ext_vector_type(4)));

#define N_CELLS 3000
#define N_GENES 1000
#define M_NODES 4000
#define NP 3072
#define MP 4096

// dual-mode scalar read: inputs are f32 (sniffed) or bf16 (hedge)
__device__ __forceinline__ float rdv(const void* p, size_t i, int isbf) {
    if (isbf) return (float)((const bf16*)p)[i];
    return ((const float*)p)[i];
}

// guarded 4-wide row load from dual-mode matrix (n x n), zero-padded
__device__ __forceinline__ f32x4 load4g(const void* A, int n, int row, int col, int isbf) {
    f32x4 v = {0.f, 0.f, 0.f, 0.f};
    if (row < n) {
        if (col + 3 < n) {
            if (isbf) {
                const u16x4 u = *(const u16x4*)((const unsigned short*)A + (size_t)row * n + col);
                #pragma unroll
                for (int k = 0; k < 4; k++) v[k] = __uint_as_float(((unsigned)u[k]) << 16);
            } else {
                v = *(const f32x4*)((const float*)A + (size_t)row * n + col);
            }
        } else {
            #pragma unroll
            for (int k = 0; k < 4; k++)
                if (col + k < n) v[k] = rdv(A, (size_t)row * n + col + k, isbf);
        }
    }
    return v;
}

__device__ __forceinline__ void async_copy16(const bf16* g, bf16* l) {
    __builtin_amdgcn_global_load_lds((const __attribute__((address_space(1))) void*)g,
                                     (__attribute__((address_space(3))) void*)l,
                                     16, 0, 0);
}

// X ~ U[0,1): as bf16 every word's low16 < 0x3F80 (~100%); as f32 ~25%.
__global__ void sniff_dtype(const unsigned int* __restrict__ X, int* __restrict__ flag)
{
    __shared__ int cnt[4];
    int t = threadIdx.x;
    int c = 0;
    for (int i = t; i < 2048; i += 256)
        if ((X[i] & 0xFFFFu) < 0x3F80u) c++;
    #pragma unroll
    for (int off = 32; off > 0; off >>= 1) c += __shfl_down(c, off);
    if ((t & 63) == 0) cnt[t >> 6] = c;
    __syncthreads();
    if (t == 0) flag[0] = (cnt[0] + cnt[1] + cnt[2] + cnt[3] > 1536) ? 1 : 0;
}

// ---------------------------------------------------------------------------
// NT GEMM, double-buffered async global->LDS staging, optional SPLIT-K:
// C[i,j] = sum_k A[i,k]*B[j,k], 128x128 tile, K%32==0, bf16 in, OutT out.
// gridDim.z = S slices (each covers K/S); ATOMIC: atomicAdd f32 partials
// (dest pre-zeroed). BIAS_ROW: C = relu(C + bias[i]) (gemm1: A=W rows are
// channels -> coalesced non-transposed store). SCALE_ROW: C *= rcp(rsum[i])
// (softmax normalize folded in; rsum==0 pad rows -> 0).
// XCD swizzle: rectangular 8x16 per-XCD chunks for 32x32 grids (d3 shape:
// 24 L2 panels/XCD vs 36 for row-chunks), bijective m204 otherwise.
// ---------------------------------------------------------------------------
template<bool BIAS_ROW, bool SCALE_ROW, bool ATOMIC, typename OutT>
__global__ __launch_bounds__(256, 2)
void gemm_nt(const bf16* __restrict__ A, int lda,
             const bf16* __restrict__ B, int ldb,
             const bf16* __restrict__ bias,
             const float* __restrict__ rsum,
             OutT* __restrict__ C, int ldc,
             int K, int mBound, int nBound)
{
    __shared__ __align__(16) bf16 As[2][128 * 32];
    __shared__ __align__(16) bf16 Bs[2][128 * 32];
    const int tid  = threadIdx.x;
    const int wave = tid >> 6;
    const int lane = tid & 63;

    const int orig = blockIdx.y * gridDim.x + blockIdx.x;
    int i0, j0;
    if (gridDim.x == 32 && gridDim.y == 32) {
        // rectangular per-XCD chunk: XCD (xr,xc) in 4x2 supergrid owns an
        // 8-row x 16-col tile rectangle
        const int xcd = orig & 7, idx = orig >> 3;
        const int r = ((xcd >> 1) << 3) + (idx >> 4);
        const int c = ((xcd & 1) << 4) + (idx & 15);
        i0 = r * 128;
        j0 = c * 128;
    } else {
        // bijective XCD swizzle (m204)
        const int nwg = gridDim.x * gridDim.y;
        const int q = nwg >> 3, rr = nwg & 7;
        const int xcd = orig & 7, idx = orig >> 3;
        const int swz = (xcd < rr ? xcd * (q + 1) : rr * (q + 1) + (xcd - rr) * q) + idx;
        i0 = (swz / gridDim.x) * 128;
        j0 = (swz % gridDim.x) * 128;
    }

    // split-K slice
    const int kSlice = K / gridDim.z;
    const int kBase  = blockIdx.z * kSlice;
    const int kEnd   = kBase + kSlice;

    // async staging: wave w covers rows [w*32, w*32+32); lane -> (srow, 8-elem k)
    const int srow = lane >> 2;          // 0..15
    const int sk   = (lane & 3) * 8;     // 0,8,16,24
    const bf16* gA0 = A + (size_t)(i0 + wave * 32 + srow) * lda + sk;
    const bf16* gA1 = gA0 + (size_t)16 * lda;
    const bf16* gB0 = B + (size_t)(j0 + wave * 32 + srow) * ldb + sk;
    const bf16* gB1 = gB0 + (size_t)16 * ldb;
    const int loA0 = (wave * 32) * 32;
    const int loA1 = (wave * 32 + 16) * 32;

    const int wm = (wave >> 1) * 64;
    const int wn = (wave & 1) * 64;
    const int fr = lane & 15;
    const int fk = (lane >> 4) * 8;

    f32x4 acc[4][4] = {};

    auto stage = [&](int buf, int kt) {
        async_copy16(gA0 + kt, &As[buf][loA0]);
        async_copy16(gA1 + kt, &As[buf][loA1]);
        async_copy16(gB0 + kt, &Bs[buf][loA0]);
        async_copy16(gB1 + kt, &Bs[buf][loA1]);
    };

    stage(0, kBase);
    __syncthreads();             // prologue drain (once)
    int cur = 0;

    for (int kt = kBase; kt < kEnd; kt += 32) {
        if (kt + 32 < kEnd) stage(cur ^ 1, kt + 32);   // prefetch next tile

        bf16x8 af[4], bfv[4];
        #pragma unroll
        for (int t = 0; t < 4; t++) {
            af[t]  = *(const bf16x8*)&As[cur][(wm + t * 16 + fr) * 32 + fk];
            bfv[t] = *(const bf16x8*)&Bs[cur][(wn + t * 16 + fr) * 32 + fk];
        }
        #pragma unroll
        for (int mt = 0; mt < 4; mt++)
            #pragma unroll
            for (int nt = 0; nt < 4; nt++)
                acc[mt][nt] = __builtin_amdgcn_mfma_f32_16x16x32_bf16(
                    af[mt], bfv[nt], acc[mt][nt], 0, 0, 0);

        __syncthreads();   // prefetch landed; reads done -> safe to flip
        cur ^= 1;
    }

    // C/D mapping: col(n)=lane&15, row(m)=(lane>>4)*4+reg
    const int ci = (lane >> 4) * 4;
    const int cj = lane & 15;
    #pragma unroll
    for (int mt = 0; mt < 4; mt++) {
        #pragma unroll
        for (int rg = 0; rg < 4; rg++) {
            const int gi = i0 + wm + mt * 16 + ci + rg;
            if (gi >= mBound) continue;
            float bv = 0.f, rc = 1.f;
            if (BIAS_ROW) bv = (float)bias[gi];
            if (SCALE_ROW) {
                const float r_ = rsum[gi];
                rc = r_ > 0.f ? __builtin_amdgcn_rcpf(r_) : 0.f;
            }
            #pragma unroll
            for (int nt = 0; nt < 4; nt++) {
                const int gj = j0 + wn + nt * 16 + cj;
                if (gj >= nBound) continue;
                float v = acc[mt][nt][rg];
                if (BIAS_ROW) { v += bv; v = v > 0.f ? v : 0.f; }
                if (SCALE_ROW) v *= rc;
                if constexpr (ATOMIC) {
                    atomicAdd((float*)&C[(size_t)gi * ldc + gj], v);
                } else {
                    C[(size_t)gi * ldc + gj] = (OutT)v;
                }
            }
        }
    }
}

// dst (rp x cp) bf16 = src (r x c, dual-mode) zero-padded
__global__ void padcopy(const void* __restrict__ src, int r, int c,
                        bf16* __restrict__ dst, int rp, int cp,
                        const int* __restrict__ flag)
{
    const int isbf = flag[0];
    long idx = (long)blockIdx.x * 256 + threadIdx.x;
    if (idx >= (long)rp * cp) return;
    int i = (int)(idx / cp), j = (int)(idx % cp);
    float v = 0.f;
    if (i < r && j < c) v = rdv(src, (size_t)i * c + j, isbf);
    dst[idx] = (bf16)v;
}

// XT (np x np bf16) = transpose of src (n x n, dual-mode), zero-padded.
__global__ void padcopy_T(const void* __restrict__ src, int n,
                          bf16* __restrict__ dst, int np,
                          const int* __restrict__ flag)
{
    __shared__ float t[32][33];
    const int isbf = flag[0];
    const int tx = threadIdx.x & 31;
    const int ty = threadIdx.x >> 5;     // 0..7
    const int i0 = blockIdx.y * 32;      // output row block (i = src col)
    const int k0 = blockIdx.x * 32;      // output col block (k = src row)
    #pragma unroll
    for (int q = 0; q < 4; q++) {        // stage src[k0+r][i0+tx]
        int k = k0 + ty + q * 8;
        float v = 0.f;
        if (k < n && i0 + tx < n) v = rdv(src, (size_t)k * n + i0 + tx, isbf);
        t[ty + q * 8][tx] = v;
    }
    __syncthreads();
    #pragma unroll
    for (int q = 0; q < 4; q++) {        // write dst[i0+r][k0+tx] = src[k0+tx][i0+r]
        int i = ty + q * 8;
        dst[(size_t)(i0 + i) * np + k0 + tx] = (bf16)t[tx][i];
    }
}

__global__ void zero_f32(float* __restrict__ p, int n)
{
    int i = blockIdx.x * 256 + threadIdx.x;
    if (i < n) p[i] = 0.f;
}

// grid-stride vectorized zero (n4 = count of float4)
__global__ void zero_f32v(f32x4* __restrict__ p, long n4)
{
    long i = (long)blockIdx.x * 256 + threadIdx.x;
    const long str = (long)gridDim.x * 256;
    const f32x4 z = {0.f, 0.f, 0.f, 0.f};
    for (; i < n4; i += str) p[i] = z;
}

// grid-stride vectorized f32 -> bf16 convert (n4 = count of 4-elem groups)
__global__ void f32_to_bf16_v4(const f32x4* __restrict__ src, bf16x4* __restrict__ dst, long n4)
{
    long i = (long)blockIdx.x * 256 + threadIdx.x;
    const long str = (long)gridDim.x * 256;
    for (; i < n4; i += str) {
        f32x4 v = src[i];
        bf16x4 w;
        #pragma unroll
        for (int k = 0; k < 4; k++) w[k] = (__bf16)v[k];
        dst[i] = w;
    }
}

// s[i] += sum_o Zt[o,i]*vt[oBase+o]; r likewise. Zt chunk-local (ld = nPad).
__global__ void scores_accum(const bf16* __restrict__ Zt, int ld,
                             int oBase, int oCount,
                             const void* __restrict__ vt, const void* __restrict__ vr,
                             float* __restrict__ s, float* __restrict__ r,
                             const int* __restrict__ flag)
{
    const int isbf = flag[0];
    const int i = blockIdx.x * 256 + threadIdx.x;
    const int o0 = blockIdx.y * 256;
    int o1 = o0 + 256; if (o1 > oCount) o1 = oCount;
    if (o0 >= o1) return;
    float as = 0.f, ar = 0.f;
    for (int o = o0; o < o1; o++) {
        float z = (float)Zt[(size_t)o * ld + i];
        as += z * rdv(vt, oBase + o, isbf);
        ar += z * rdv(vr, oBase + o, isbf);
    }
    atomicAdd(&s[i], as);
    atomicAdd(&r[i], ar);
}

// ---------------------------------------------------------------------------
// Paired E-pass: block (bi<=bj) computes E tiles (I,J) and (J,I), 64x64 each.
// E[i,j] = exp(sigmoid(A[i,j]*(s[j]+vtb) + A[j,i]*(r[i]+vrb))), i,j<n else 0.
// Score biases folded in (replaces a separate scores_bias launch).
// ---------------------------------------------------------------------------
__global__ __launch_bounds__(256)
void e_pass_pair(const void* __restrict__ A, int n,
                 const float* __restrict__ s, const float* __restrict__ r,
                 const void* __restrict__ vtb, const void* __restrict__ vrb,
                 bf16* __restrict__ E, int ldE, float* __restrict__ rowsum,
                 const int* __restrict__ flag)
{
    __shared__ float T1t[64][65];   // T1t[a][b] = A[i0+b][j0+a]
    __shared__ float T2t[64][65];   // T2t[a][b] = A[j0+b][i0+a]
    const int bi = blockIdx.y, bj = blockIdx.x;
    if (bj < bi) return;
    const int isbf = flag[0];
    const int tid = threadIdx.x;
    const int i0 = bi * 64, j0 = bj * 64;
    const int tx = tid & 15;         // col group: 4 consecutive cols
    const int ty = tid >> 4;         // 0..15
    const int c0 = 4 * tx;
    const float bt = rdv(vtb, 0, isbf);
    const float br = rdv(vrb, 0, isbf);

    #pragma unroll
    for (int rr = 0; rr < 4; rr++) {
        const int rw = ty + 16 * rr;                       // 0..63
        f32x4 v1 = load4g(A, n, i0 + rw, j0 + c0, isbf);   // region1 row
        f32x4 v2 = load4g(A, n, j0 + rw, i0 + c0, isbf);   // region2 row
        #pragma unroll
        for (int k = 0; k < 4; k++) {
            T1t[c0 + k][rw] = v1[k];
            T2t[c0 + k][rw] = v2[k];
        }
    }
    __syncthreads();

    const float LOG2E = 1.442695041f;

    // ---- tile1: rows I, cols J ----
    {
        f32x4 s4 = *(const f32x4*)&s[j0 + c0];
        #pragma unroll
        for (int k = 0; k < 4; k++) s4[k] += bt;
        #pragma unroll
        for (int q = 0; q < 4; q++) {
            const int li = ty + 16 * q;
            const int gi = i0 + li;
            const float rv = r[gi] + br;
            const f32x4 a = load4g(A, n, gi, j0 + c0, isbf);
            f32x4 ev;
            float part = 0.f;
            #pragma unroll
            for (int k = 0; k < 4; k++) {
                const float trn = T2t[li][c0 + k];             // A[gj][gi]
                const float x = a[k] * s4[k] + trn * rv;
                const float t = __builtin_amdgcn_exp2f(-x * LOG2E);
                const float sig = __builtin_amdgcn_rcpf(1.f + t);
                float e = __builtin_amdgcn_exp2f(sig * LOG2E);
                const int gj = j0 + c0 + k;
                e = (gi < n && gj < n) ? e : 0.f;
                ev[k] = e;
                part += e;
            }
            bf16x4 w;
            #pragma unroll
            for (int k = 0; k < 4; k++) w[k] = (__bf16)ev[k];
            *(bf16x4*)&E[(size_t)gi * ldE + j0 + c0] = w;
            part += __shfl_down(part, 8, 16);
            part += __shfl_down(part, 4, 16);
            part += __shfl_down(part, 2, 16);
            part += __shfl_down(part, 1, 16);
            if (tx == 0) atomicAdd(&rowsum[gi], part);
        }
    }

    // ---- tile2: rows J, cols I (skip on diagonal) ----
    if (bj > bi) {
        f32x4 s4 = *(const f32x4*)&s[i0 + c0];
        #pragma unroll
        for (int k = 0; k < 4; k++) s4[k] += bt;
        #pragma unroll
        for (int q = 0; q < 4; q++) {
            const int lr = ty + 16 * q;
            const int gr = j0 + lr;
            const float rv = r[gr] + br;
            const f32x4 a = load4g(A, n, gr, i0 + c0, isbf);
            f32x4 ev;
            float part = 0.f;
            #pragma unroll
            for (int k = 0; k < 4; k++) {
                const float trn = T1t[lr][c0 + k];             // A[gj][gr]
                const float x = a[k] * s4[k] + trn * rv;
                const float t = __builtin_amdgcn_exp2f(-x * LOG2E);
                const float sig = __builtin_amdgcn_rcpf(1.f + t);
                float e = __builtin_amdgcn_exp2f(sig * LOG2E);
                const int gj = i0 + c0 + k;
                e = (gr < n && gj < n) ? e : 0.f;
                ev[k] = e;
                part += e;
            }
            bf16x4 w;
            #pragma unroll
            for (int k = 0; k < 4; k++) w[k] = (__bf16)ev[k];
            *(bf16x4*)&E[(size_t)gr * ldE + i0 + c0] = w;
            part += __shfl_down(part, 8, 16);
            part += __shfl_down(part, 4, 16);
            part += __shfl_down(part, 2, 16);
            part += __shfl_down(part, 1, 16);
            if (tx == 0) atomicAdd(&rowsum[gr], part);
        }
    }
}

// D (MP x 128): rows m<G from gG[c,m] (dual); rows G..M-1 from H3[m-G,c]; else 0
__global__ void build_D(const void* __restrict__ gG, const bf16* __restrict__ H3,
                        bf16* __restrict__ D, const int* __restrict__ flag)
{
    const int isbf = flag[0];
    int idx = blockIdx.x * 256 + threadIdx.x;
    int m = idx >> 7, c = idx & 127;
    float v = 0.f;
    if (c < 64) {
        if (m < N_GENES)      v = rdv(gG, (size_t)c * N_GENES + m, isbf);
        else if (m < M_NODES) v = (float)H3[(size_t)(m - N_GENES) * 128 + c];
    }
    D[idx] = (bf16)v;
}

extern "C" void kernel_launch(void* const* d_in, const int* in_sizes, int n_in,
                              void* d_out, int out_size, void* d_ws, size_t ws_size,
                              hipStream_t stream)
{
    const void* X     = d_in[0];
    const void* A_enc = d_in[1];
    const void* A_dec = d_in[2];
    const void* gG    = d_in[3];
    const void *W[7], *Wb[7], *vt[7], *vtb[7], *vr[7], *vrb[7];
    for (int l = 0; l < 7; l++) {
        W[l]   = d_in[4 + 6 * l + 0];
        Wb[l]  = d_in[4 + 6 * l + 1];
        vt[l]  = d_in[4 + 6 * l + 2];
        vtb[l] = d_in[4 + 6 * l + 3];
        vr[l]  = d_in[4 + 6 * l + 4];
        vrb[l] = d_in[4 + 6 * l + 5];
    }

    const int fop[7] = {512, 256, 128, 256, 512, 4096, 1024};
    const int fip[7] = {3072, 512, 256, 128, 256, 512, 512};
    const int foR[7] = {512, 256, 64, 256, 512, 4000, 1000};
    const int fiR[7] = {3000, 512, 256, 64, 256, 512, 512};

    // ZT capacity: full-Z (4096 cols, 32 MB) -> d3 gemm2 is ONE 4096^3
    // dispatch. Gate on ws_size; else verified chunked fallback.
    const int CHcap = (ws_size >= (size_t)100 * 1024 * 1024) ? 4096 : 1024;

    // ---- workspace layout, small first ----
    char* ws = (char*)d_ws;
    size_t off = 0;
    auto alloc = [&](size_t bytes) -> void* {
        void* p = ws + off;
        off += (bytes + 255) & ~(size_t)255;
        return p;
    };
    int*   flag = (int*)alloc(256);
    float* sb   = (float*)alloc((size_t)MP * 4);   // sb, rb, rsum contiguous
    float* rb   = (float*)alloc((size_t)MP * 4);
    float* rsum = (float*)alloc((size_t)MP * 4);
    bf16* Bp[7];
    for (int l = 0; l < 7; l++) Bp[l] = (bf16*)alloc((size_t)fop[l] * 2);
    bf16* RA = (bf16*)alloc((size_t)NP * 512 * 2);   // H1 -> H3 -> D1
    bf16* RB = (bf16*)alloc((size_t)NP * 256 * 2);   // H2 -> Dd
    bf16* RC = (bf16*)alloc((size_t)MP * 512 * 2);   // D2
    bf16 *H1 = RA, *H3 = RA, *D1 = RA;
    bf16 *H2 = RB, *Dd = RB;
    bf16 *D2 = RC;
    bf16* Wp[7];
    for (int l = 0; l < 7; l++) Wp[l] = (bf16*)alloc((size_t)fop[l] * fip[l] * 2);
    float* Hf = (float*)alloc((size_t)MP * 512 * 4);        // 8 MB split-K f32 accum
    bf16*  ZT = (bf16*)alloc((size_t)CHcap * MP * 2);       // 8 or 32 MB
    bf16*  E  = (bf16*)alloc((size_t)MP * MP * 2);          // 32 MB
    // XT = pad(X^T) bf16 (NP x NP, 18 MB) aliases E: consumed by layer-0
    // gemm1 before e_pass (first writer of E) runs.
    bf16* XT = E;

    // split-K slice count for contraction length Kc: only for small grids
    // (base < 192 blocks); want grid >= ~768; slice >= 256 K-elems.
    auto pickS = [](int base, int Kc) -> int {
        if (base >= 192) return 1;
        const int steps = Kc / 32;
        int best = 1;
        for (int S = 1; S <= 16; S++) {
            if (steps % S) continue;
            if (Kc / S < 256) continue;
            if (base * S > 1536) break;
            best = S;
            if (base * S >= 768) break;
        }
        return best;
    };

    // ---- prep ----
    sniff_dtype<<<1, 256, 0, stream>>>((const unsigned int*)X, flag);
    for (int l = 0; l < 7; l++) {
        long tot = (long)fop[l] * fip[l];
        padcopy<<<dim3((unsigned)((tot + 255) / 256)), 256, 0, stream>>>(
            W[l], foR[l], fiR[l], Wp[l], fop[l], fip[l], flag);
        padcopy<<<dim3((fop[l] + 255) / 256), 256, 0, stream>>>(
            Wb[l], 1, foR[l], Bp[l], 1, fop[l], flag);
    }
    padcopy_T<<<dim3(NP / 32, NP / 32), 256, 0, stream>>>(X, N_CELLS, XT, NP, flag);

    // HoutB != null: intermediate -> split-K atomic into Hf (f32, ld=nBtot),
    // then f32->bf16 convert. HoutB == null: output layer -> direct f32
    // stores; d4-shape (base grid 256) uses S=2 atomic with pre-zero.
    auto layer = [&](const bf16* Hin, int l, const void* Araw,
                     int nReal, int nPad, bf16* HoutB, float* HoutF,
                     int ldOut, int mB, int nBtot) {
        const int K = fip[l], NO = fop[l];
        const int CH = NO > CHcap ? CHcap : NO;
        const int nch = NO / CH;
        // gemm1 (operandswapped): ZT[o,i] = relu(sum_k W[o,k]*Hin[i,k]+b[o]).
        // A = W rows (channels), bias by row -> coalesced direct store.
        auto gemm1 = [&](int c) {
            gemm_nt<true, false, false, bf16><<<dim3(nPad / 128, CH / 128), 256, 0, stream>>>(
                Wp[l] + (size_t)c * CH * K, K, Hin, K, Bp[l] + c * CH, nullptr,
                ZT, nPad, K, CH, nPad);
        };
        // pass A: scores (sb, rb, rsum zeroed in one launch — contiguous)
        zero_f32<<<dim3(3 * MP / 256), 256, 0, stream>>>(sb, 3 * MP);
        for (int c = 0; c < nch; c++) {
            gemm1(c);
            int oBase = c * CH;
            int oCnt = foR[l] - oBase;
            if (oCnt > CH) oCnt = CH;
            if (oCnt > 0)
                scores_accum<<<dim3(nPad / 256, (unsigned)((oCnt + 255) / 256)), 256, 0, stream>>>(
                    ZT, nPad, oBase, oCnt, vt[l], vr[l], sb, rb, flag);
        }
        // full E + row sums (score biases folded in)
        e_pass_pair<<<dim3(nPad / 64, nPad / 64), 256, 0, stream>>>(
            Araw, nReal, sb, rb, vtb[l], vrb[l], E, nPad, rsum, flag);
        // pass B: gemm2 (contraction = nPad E-columns), softmax scale folded
        // into the epilogue via rcp(rsum).
        if (HoutB)
            zero_f32v<<<2048, 256, 0, stream>>>((f32x4*)Hf, (long)nPad * nBtot / 4);
        for (int c = 0; c < nch; c++) {
            if (nch > 1) gemm1(c);   // ZT intact when nch==1
            int colBase = c * CH;
            int nB = nBtot - colBase;
            if (nB > CH) nB = CH;
            if (nB <= 0) continue;
            const int bx = CH / 128, by = nPad / 128;
            if (HoutB) {
                const int S = pickS(bx * by, nPad);
                gemm_nt<false, true, true, float><<<dim3(bx, by, S), 256, 0, stream>>>(
                    E, nPad, ZT, nPad, nullptr, rsum,
                    Hf + colBase, nBtot, nPad, nPad, nB);
            } else {
                // output layer: S=2 atomic only for the 1-block/CU shape
                const int S = (nch == 1 && bx * by == 256) ? 2 : 1;
                if (S == 2) {
                    zero_f32v<<<2048, 256, 0, stream>>>(
                        (f32x4*)HoutF, (long)mB * ldOut / 4);
                    gemm_nt<false, true, true, float><<<dim3(bx, by, S), 256, 0, stream>>>(
                        E, nPad, ZT, nPad, nullptr, rsum,
                        HoutF + colBase, ldOut, nPad, mB, nB);
                } else {
                    gemm_nt<false, true, false, float><<<dim3(bx, by), 256, 0, stream>>>(
                        E, nPad, ZT, nPad, nullptr, rsum,
                        HoutF + colBase, ldOut, nPad, mB, nB);
                }
            }
        }
        if (HoutB)
            f32_to_bf16_v4<<<2048, 256, 0, stream>>>(
                (const f32x4*)Hf, (bf16x4*)HoutB, (long)nPad * nBtot / 4);
    };

    // encoder (H0 = X^T staged as XT by padcopy_T)
    layer(XT,      0, A_enc, N_CELLS, NP, H1, nullptr, 512, NP, 512);
    layer(H1,      1, A_enc, N_CELLS, NP, H2, nullptr, 256, NP, 256);
    layer(H2,      2, A_enc, N_CELLS, NP, H3, nullptr, 128, NP, 128);
    // decoder input D = concat([gG, H3^T], axis=1)^T
    build_D<<<dim3((MP * 128) / 256), 256, 0, stream>>>(gG, H3, Dd, flag);
    layer(Dd, 3, A_dec, M_NODES, MP, D1, nullptr, 256, MP, 256);
    layer(D1, 4, A_dec, M_NODES, MP, D2, nullptr, 512, MP, 512);
    // outputs are float32 (reference dtype)
    float* outCell = (float*)d_out;
    float* outGene = outCell + (size_t)M_NODES * M_NODES;
    layer(D2, 5, A_dec, M_NODES, MP, nullptr, outCell, 4000, 4000, 4000);
    layer(D2, 6, A_dec, M_NODES, MP, nullptr, outGene, 1000, 4000, 1000);
}

// Round 8
// 1248.495 us; speedup vs baseline: 2.0380x; 1.4424x over previous
//
#include <hip/hip_runtime.h>
#include <hip/hip_bf16.h>

using bf16 = __hip_bfloat16;
typedef __bf16 bf16x8 __attribute__((ext_vector_type(8)));
typedef __bf16 bf16x4 __attribute__((ext_vector_type(4)));
typedef float f32x4 __attribute__((ext_vector_type(4)));
typedef unsigned short u16x4 __attribute__((ext_vector_type(4)));

#define N_CELLS 3000
#define N_GENES 1000
#define M_NODES 4000
#define NP 3072
#define MP 4096

// dual-mode scalar read: inputs are f32 (sniffed) or bf16 (hedge)
__device__ __forceinline__ float rdv(const void* p, size_t i, int isbf) {
    if (isbf) return (float)((const bf16*)p)[i];
    return ((const float*)p)[i];
}

// guarded 4-wide row load from dual-mode matrix (n x n), zero-padded
__device__ __forceinline__ f32x4 load4g(const void* A, int n, int row, int col, int isbf) {
    f32x4 v = {0.f, 0.f, 0.f, 0.f};
    if (row < n) {
        if (col + 3 < n) {
            if (isbf) {
                const u16x4 u = *(const u16x4*)((const unsigned short*)A + (size_t)row * n + col);
                #pragma unroll
                for (int k = 0; k < 4; k++) v[k] = __uint_as_float(((unsigned)u[k]) << 16);
            } else {
                v = *(const f32x4*)((const float*)A + (size_t)row * n + col);
            }
        } else {
            #pragma unroll
            for (int k = 0; k < 4; k++)
                if (col + k < n) v[k] = rdv(A, (size_t)row * n + col + k, isbf);
        }
    }
    return v;
}

// unguarded 4-wide load from padded bf16 matrix (stride ld)
__device__ __forceinline__ f32x4 load4b(const bf16* A, int ld, int row, int col) {
    const u16x4 u = *(const u16x4*)((const unsigned short*)A + (size_t)row * ld + col);
    f32x4 v;
    #pragma unroll
    for (int k = 0; k < 4; k++) v[k] = __uint_as_float(((unsigned)u[k]) << 16);
    return v;
}

__device__ __forceinline__ void async_copy16(const bf16* g, bf16* l) {
    __builtin_amdgcn_global_load_lds((const __attribute__((address_space(1))) void*)g,
                                     (__attribute__((address_space(3))) void*)l,
                                     16, 0, 0);
}

// X ~ U[0,1): as bf16 every word's low16 < 0x3F80 (~100%); as f32 ~25%.
__global__ void sniff_dtype(const unsigned int* __restrict__ X, int* __restrict__ flag)
{
    __shared__ int cnt[4];
    int t = threadIdx.x;
    int c = 0;
    for (int i = t; i < 2048; i += 256)
        if ((X[i] & 0xFFFFu) < 0x3F80u) c++;
    #pragma unroll
    for (int off = 32; off > 0; off >>= 1) c += __shfl_down(c, off);
    if ((t & 63) == 0) cnt[t >> 6] = c;
    __syncthreads();
    if (t == 0) flag[0] = (cnt[0] + cnt[1] + cnt[2] + cnt[3] > 1536) ? 1 : 0;
}

// ---------------------------------------------------------------------------
// NT GEMM, double-buffered async global->LDS staging, optional SPLIT-K:
// C[i,j] = sum_k A[i,k]*B[j,k], 128x128 tile, K%32==0, bf16 in, OutT out.
// BIAS_ROW: C = relu(C + bias[i]). SCALE_ROW: C *= rcp(rsum[i]) (pad rows->0).
// ATOMIC: atomicAdd f32 partials (dest pre-zeroed), gridDim.z = K slices.
// SCORES (gemm1 fusion): sAcc[j] += sum_i C[i,j]*vt[oBase+i] (i<oBound),
// rAcc likewise — per-column partials reduced via shfl, one atomic/col/wave.
// XCD swizzle: rectangular 8x16 per-XCD chunks for 32x32 grids, else m204.
// ---------------------------------------------------------------------------
template<bool BIAS_ROW, bool SCALE_ROW, bool ATOMIC, bool SCORES, typename OutT>
__global__ __launch_bounds__(256, 2)
void gemm_nt(const bf16* __restrict__ A, int lda,
             const bf16* __restrict__ B, int ldb,
             const bf16* __restrict__ bias,
             const float* __restrict__ rsum,
             OutT* __restrict__ C, int ldc,
             int K, int mBound, int nBound,
             const void* __restrict__ vtp, const void* __restrict__ vrp,
             const int* __restrict__ flag, int oBase, int oBound,
             float* __restrict__ sAcc, float* __restrict__ rAcc)
{
    __shared__ __align__(16) bf16 As[2][128 * 32];
    __shared__ __align__(16) bf16 Bs[2][128 * 32];
    const int tid  = threadIdx.x;
    const int wave = tid >> 6;
    const int lane = tid & 63;

    const int orig = blockIdx.y * gridDim.x + blockIdx.x;
    int i0, j0;
    if (gridDim.x == 32 && gridDim.y == 32) {
        // rectangular per-XCD chunk: XCD owns an 8-row x 16-col tile rect
        const int xcd = orig & 7, idx = orig >> 3;
        const int r = ((xcd >> 1) << 3) + (idx >> 4);
        const int c = ((xcd & 1) << 4) + (idx & 15);
        i0 = r * 128;
        j0 = c * 128;
    } else {
        // bijective XCD swizzle (m204)
        const int nwg = gridDim.x * gridDim.y;
        const int q = nwg >> 3, rr = nwg & 7;
        const int xcd = orig & 7, idx = orig >> 3;
        const int swz = (xcd < rr ? xcd * (q + 1) : rr * (q + 1) + (xcd - rr) * q) + idx;
        i0 = (swz / gridDim.x) * 128;
        j0 = (swz % gridDim.x) * 128;
    }

    // split-K slice
    const int kSlice = K / gridDim.z;
    const int kBase  = blockIdx.z * kSlice;
    const int kEnd   = kBase + kSlice;

    // async staging: wave w covers rows [w*32, w*32+32); lane -> (srow, 8-elem k)
    const int srow = lane >> 2;          // 0..15
    const int sk   = (lane & 3) * 8;     // 0,8,16,24
    const bf16* gA0 = A + (size_t)(i0 + wave * 32 + srow) * lda + sk;
    const bf16* gA1 = gA0 + (size_t)16 * lda;
    const bf16* gB0 = B + (size_t)(j0 + wave * 32 + srow) * ldb + sk;
    const bf16* gB1 = gB0 + (size_t)16 * ldb;
    const int loA0 = (wave * 32) * 32;
    const int loA1 = (wave * 32 + 16) * 32;

    const int wm = (wave >> 1) * 64;
    const int wn = (wave & 1) * 64;
    const int fr = lane & 15;
    const int fk = (lane >> 4) * 8;

    f32x4 acc[4][4] = {};

    auto stage = [&](int buf, int kt) {
        async_copy16(gA0 + kt, &As[buf][loA0]);
        async_copy16(gA1 + kt, &As[buf][loA1]);
        async_copy16(gB0 + kt, &Bs[buf][loA0]);
        async_copy16(gB1 + kt, &Bs[buf][loA1]);
    };

    stage(0, kBase);
    __syncthreads();             // prologue drain (once)
    int cur = 0;

    for (int kt = kBase; kt < kEnd; kt += 32) {
        if (kt + 32 < kEnd) stage(cur ^ 1, kt + 32);   // prefetch next tile

        bf16x8 af[4], bfv[4];
        #pragma unroll
        for (int t = 0; t < 4; t++) {
            af[t]  = *(const bf16x8*)&As[cur][(wm + t * 16 + fr) * 32 + fk];
            bfv[t] = *(const bf16x8*)&Bs[cur][(wn + t * 16 + fr) * 32 + fk];
        }
        #pragma unroll
        for (int mt = 0; mt < 4; mt++)
            #pragma unroll
            for (int nt = 0; nt < 4; nt++)
                acc[mt][nt] = __builtin_amdgcn_mfma_f32_16x16x32_bf16(
                    af[mt], bfv[nt], acc[mt][nt], 0, 0, 0);

        __syncthreads();   // prefetch landed; reads done -> safe to flip
        cur ^= 1;
    }

    // C/D mapping: col(n)=lane&15, row(m)=(lane>>4)*4+reg
    const int ci = (lane >> 4) * 4;
    const int cj = lane & 15;
    int isbf = 0;
    if constexpr (SCORES) isbf = flag[0];
    float ps[4] = {0.f, 0.f, 0.f, 0.f};
    float pr[4] = {0.f, 0.f, 0.f, 0.f};
    #pragma unroll
    for (int mt = 0; mt < 4; mt++) {
        #pragma unroll
        for (int rg = 0; rg < 4; rg++) {
            const int gi = i0 + wm + mt * 16 + ci + rg;
            if (gi >= mBound) continue;
            float bv = 0.f, rc = 1.f;
            if (BIAS_ROW) bv = (float)bias[gi];
            if (SCALE_ROW) {
                const float r_ = rsum[gi];
                rc = r_ > 0.f ? __builtin_amdgcn_rcpf(r_) : 0.f;
            }
            float vtv = 0.f, vrv = 0.f;
            if constexpr (SCORES) {
                if (gi < oBound) {
                    vtv = rdv(vtp, (size_t)(oBase + gi), isbf);
                    vrv = rdv(vrp, (size_t)(oBase + gi), isbf);
                }
            }
            #pragma unroll
            for (int nt = 0; nt < 4; nt++) {
                const int gj = j0 + wn + nt * 16 + cj;
                if (gj >= nBound) continue;
                float v = acc[mt][nt][rg];
                if (BIAS_ROW) { v += bv; v = v > 0.f ? v : 0.f; }
                if (SCALE_ROW) v *= rc;
                if constexpr (ATOMIC) {
                    atomicAdd((float*)&C[(size_t)gi * ldc + gj], v);
                } else {
                    C[(size_t)gi * ldc + gj] = (OutT)v;
                }
                if constexpr (SCORES) {
                    ps[nt] += v * vtv;
                    pr[nt] += v * vrv;
                }
            }
        }
    }
    if constexpr (SCORES) {
        // lanes sharing a column are 16 apart: reduce 4 -> lane<16
        #pragma unroll
        for (int nt = 0; nt < 4; nt++) {
            float p = ps[nt], r2 = pr[nt];
            p  += __shfl_down(p, 32);  p  += __shfl_down(p, 16);
            r2 += __shfl_down(r2, 32); r2 += __shfl_down(r2, 16);
            if (lane < 16) {
                const int gj = j0 + wn + nt * 16 + lane;
                if (gj < nBound) {
                    atomicAdd(&sAcc[gj], p);
                    atomicAdd(&rAcc[gj], r2);
                }
            }
        }
    }
}

// dst (rp x cp) bf16 = src (r x c, dual-mode) zero-padded
__global__ void padcopy(const void* __restrict__ src, int r, int c,
                        bf16* __restrict__ dst, int rp, int cp,
                        const int* __restrict__ flag)
{
    const int isbf = flag[0];
    long idx = (long)blockIdx.x * 256 + threadIdx.x;
    if (idx >= (long)rp * cp) return;
    int i = (int)(idx / cp), j = (int)(idx % cp);
    float v = 0.f;
    if (i < r && j < c) v = rdv(src, (size_t)i * c + j, isbf);
    dst[idx] = (bf16)v;
}

// XT (np x np bf16) = transpose of src (n x n, dual-mode), zero-padded.
__global__ void padcopy_T(const void* __restrict__ src, int n,
                          bf16* __restrict__ dst, int np,
                          const int* __restrict__ flag)
{
    __shared__ float t[32][33];
    const int isbf = flag[0];
    const int tx = threadIdx.x & 31;
    const int ty = threadIdx.x >> 5;     // 0..7
    const int i0 = blockIdx.y * 32;      // output row block (i = src col)
    const int k0 = blockIdx.x * 32;      // output col block (k = src row)
    #pragma unroll
    for (int q = 0; q < 4; q++) {        // stage src[k0+r][i0+tx]
        int k = k0 + ty + q * 8;
        float v = 0.f;
        if (k < n && i0 + tx < n) v = rdv(src, (size_t)k * n + i0 + tx, isbf);
        t[ty + q * 8][tx] = v;
    }
    __syncthreads();
    #pragma unroll
    for (int q = 0; q < 4; q++) {        // write dst[i0+r][k0+tx] = src[k0+tx][i0+r]
        int i = ty + q * 8;
        dst[(size_t)(i0 + i) * np + k0 + tx] = (bf16)t[tx][i];
    }
}

__global__ void zero_f32(float* __restrict__ p, int n)
{
    int i = blockIdx.x * 256 + threadIdx.x;
    if (i < n) p[i] = 0.f;
}

// grid-stride vectorized zero (n4 = count of float4)
__global__ void zero_f32v(f32x4* __restrict__ p, long n4)
{
    long i = (long)blockIdx.x * 256 + threadIdx.x;
    const long str = (long)gridDim.x * 256;
    const f32x4 z = {0.f, 0.f, 0.f, 0.f};
    for (; i < n4; i += str) p[i] = z;
}

// grid-stride vectorized f32 -> bf16 convert (n4 = count of 4-elem groups)
__global__ void f32_to_bf16_v4(const f32x4* __restrict__ src, bf16x4* __restrict__ dst, long n4)
{
    long i = (long)blockIdx.x * 256 + threadIdx.x;
    const long str = (long)gridDim.x * 256;
    for (; i < n4; i += str) {
        f32x4 v = src[i];
        bf16x4 w;
        #pragma unroll
        for (int k = 0; k < 4; k++) w[k] = (__bf16)v[k];
        dst[i] = w;
    }
}

// ---------------------------------------------------------------------------
// Paired E-pass: block (bi<=bj) computes E tiles (I,J) and (J,I), 64x64 each.
// E[i,j] = exp(sigmoid(A[i,j]*(s[j]+vtb) + A[j,i]*(r[i]+vrb))), i,j<n else 0.
// CB=true: A is padded bf16 with row stride ldA (unguarded vector loads).
// CB=false: A is raw dual-mode n x n (guarded loads via flag).
// ---------------------------------------------------------------------------
template<bool CB>
__global__ __launch_bounds__(256)
void e_pass_pair(const void* __restrict__ A, int ldA, int n,
                 const float* __restrict__ s, const float* __restrict__ r,
                 const void* __restrict__ vtb, const void* __restrict__ vrb,
                 bf16* __restrict__ E, int ldE, float* __restrict__ rowsum,
                 const int* __restrict__ flag)
{
    __shared__ float T1t[64][65];   // T1t[a][b] = A[i0+b][j0+a]
    __shared__ float T2t[64][65];   // T2t[a][b] = A[j0+b][i0+a]
    const int bi = blockIdx.y, bj = blockIdx.x;
    if (bj < bi) return;
    const int isbf = flag[0];
    const int tid = threadIdx.x;
    const int i0 = bi * 64, j0 = bj * 64;
    const int tx = tid & 15;         // col group: 4 consecutive cols
    const int ty = tid >> 4;         // 0..15
    const int c0 = 4 * tx;
    const float bt = rdv(vtb, 0, isbf);
    const float br = rdv(vrb, 0, isbf);

    auto ld4 = [&](int row, int col) -> f32x4 {
        if constexpr (CB) return load4b((const bf16*)A, ldA, row, col);
        else              return load4g(A, n, row, col, isbf);
    };

    #pragma unroll
    for (int rr = 0; rr < 4; rr++) {
        const int rw = ty + 16 * rr;                       // 0..63
        f32x4 v1 = ld4(i0 + rw, j0 + c0);                  // region1 row
        f32x4 v2 = ld4(j0 + rw, i0 + c0);                  // region2 row
        #pragma unroll
        for (int k = 0; k < 4; k++) {
            T1t[c0 + k][rw] = v1[k];
            T2t[c0 + k][rw] = v2[k];
        }
    }
    __syncthreads();

    const float LOG2E = 1.442695041f;

    // ---- tile1: rows I, cols J ----
    {
        f32x4 s4 = *(const f32x4*)&s[j0 + c0];
        #pragma unroll
        for (int k = 0; k < 4; k++) s4[k] += bt;
        #pragma unroll
        for (int q = 0; q < 4; q++) {
            const int li = ty + 16 * q;
            const int gi = i0 + li;
            const float rv = r[gi] + br;
            const f32x4 a = ld4(gi, j0 + c0);
            f32x4 ev;
            float part = 0.f;
            #pragma unroll
            for (int k = 0; k < 4; k++) {
                const float trn = T2t[li][c0 + k];             // A[gj][gi]
                const float x = a[k] * s4[k] + trn * rv;
                const float t = __builtin_amdgcn_exp2f(-x * LOG2E);
                const float sig = __builtin_amdgcn_rcpf(1.f + t);
                float e = __builtin_amdgcn_exp2f(sig * LOG2E);
                const int gj = j0 + c0 + k;
                e = (gi < n && gj < n) ? e : 0.f;
                ev[k] = e;
                part += e;
            }
            bf16x4 w;
            #pragma unroll
            for (int k = 0; k < 4; k++) w[k] = (__bf16)ev[k];
            *(bf16x4*)&E[(size_t)gi * ldE + j0 + c0] = w;
            part += __shfl_down(part, 8, 16);
            part += __shfl_down(part, 4, 16);
            part += __shfl_down(part, 2, 16);
            part += __shfl_down(part, 1, 16);
            if (tx == 0) atomicAdd(&rowsum[gi], part);
        }
    }

    // ---- tile2: rows J, cols I (skip on diagonal) ----
    if (bj > bi) {
        f32x4 s4 = *(const f32x4*)&s[i0 + c0];
        #pragma unroll
        for (int k = 0; k < 4; k++) s4[k] += bt;
        #pragma unroll
        for (int q = 0; q < 4; q++) {
            const int lr = ty + 16 * q;
            const int gr = j0 + lr;
            const float rv = r[gr] + br;
            const f32x4 a = ld4(gr, i0 + c0);
            f32x4 ev;
            float part = 0.f;
            #pragma unroll
            for (int k = 0; k < 4; k++) {
                const float trn = T1t[lr][c0 + k];             // A[gj][gr]
                const float x = a[k] * s4[k] + trn * rv;
                const float t = __builtin_amdgcn_exp2f(-x * LOG2E);
                const float sig = __builtin_amdgcn_rcpf(1.f + t);
                float e = __builtin_amdgcn_exp2f(sig * LOG2E);
                const int gj = i0 + c0 + k;
                e = (gr < n && gj < n) ? e : 0.f;
                ev[k] = e;
                part += e;
            }
            bf16x4 w;
            #pragma unroll
            for (int k = 0; k < 4; k++) w[k] = (__bf16)ev[k];
            *(bf16x4*)&E[(size_t)gr * ldE + i0 + c0] = w;
            part += __shfl_down(part, 8, 16);
            part += __shfl_down(part, 4, 16);
            part += __shfl_down(part, 2, 16);
            part += __shfl_down(part, 1, 16);
            if (tx == 0) atomicAdd(&rowsum[gr], part);
        }
    }
}

// D (MP x 128): rows m<G from gG[c,m] (dual); rows G..M-1 from H3[m-G,c]; else 0
__global__ void build_D(const void* __restrict__ gG, const bf16* __restrict__ H3,
                        bf16* __restrict__ D, const int* __restrict__ flag)
{
    const int isbf = flag[0];
    int idx = blockIdx.x * 256 + threadIdx.x;
    int m = idx >> 7, c = idx & 127;
    float v = 0.f;
    if (c < 64) {
        if (m < N_GENES)      v = rdv(gG, (size_t)c * N_GENES + m, isbf);
        else if (m < M_NODES) v = (float)H3[(size_t)(m - N_GENES) * 128 + c];
    }
    D[idx] = (bf16)v;
}

extern "C" void kernel_launch(void* const* d_in, const int* in_sizes, int n_in,
                              void* d_out, int out_size, void* d_ws, size_t ws_size,
                              hipStream_t stream)
{
    const void* X     = d_in[0];
    const void* A_enc = d_in[1];
    const void* A_dec = d_in[2];
    const void* gG    = d_in[3];
    const void *W[7], *Wb[7], *vt[7], *vtb[7], *vr[7], *vrb[7];
    for (int l = 0; l < 7; l++) {
        W[l]   = d_in[4 + 6 * l + 0];
        Wb[l]  = d_in[4 + 6 * l + 1];
        vt[l]  = d_in[4 + 6 * l + 2];
        vtb[l] = d_in[4 + 6 * l + 3];
        vr[l]  = d_in[4 + 6 * l + 4];
        vrb[l] = d_in[4 + 6 * l + 5];
    }

    const int fop[7] = {512, 256, 128, 256, 512, 4096, 1024};
    const int fip[7] = {3072, 512, 256, 128, 256, 512, 512};
    const int foR[7] = {512, 256, 64, 256, 512, 4000, 1000};
    const int fiR[7] = {3000, 512, 256, 64, 256, 512, 512};

    // gates: full-Z ZT (32 MB) at ws>=100 MB; bf16 A-cache (+32 MB) at >=130.
    const int  CHcap = (ws_size >= (size_t)100 * 1024 * 1024) ? 4096 : 1024;
    const bool useAB = (ws_size >= (size_t)130 * 1024 * 1024);

    // ---- workspace layout, small first ----
    char* ws = (char*)d_ws;
    size_t off = 0;
    auto alloc = [&](size_t bytes) -> void* {
        void* p = ws + off;
        off += (bytes + 255) & ~(size_t)255;
        return p;
    };
    int*   flag = (int*)alloc(256);
    float* sb   = (float*)alloc((size_t)MP * 4);   // sb, rb, rsum contiguous
    float* rb   = (float*)alloc((size_t)MP * 4);
    float* rsum = (float*)alloc((size_t)MP * 4);
    bf16* Bp[7];
    for (int l = 0; l < 7; l++) Bp[l] = (bf16*)alloc((size_t)fop[l] * 2);
    bf16* RA = (bf16*)alloc((size_t)NP * 512 * 2);   // H1 -> H3 -> D1
    bf16* RB = (bf16*)alloc((size_t)NP * 256 * 2);   // H2 -> Dd
    bf16* RC = (bf16*)alloc((size_t)MP * 512 * 2);   // D2
    bf16 *H1 = RA, *H3 = RA, *D1 = RA;
    bf16 *H2 = RB, *Dd = RB;
    bf16 *D2 = RC;
    bf16* Wp[7];
    for (int l = 0; l < 7; l++) Wp[l] = (bf16*)alloc((size_t)fop[l] * fip[l] * 2);
    float* Hf = (float*)alloc((size_t)MP * 512 * 4);        // 8 MB split-K f32 accum
    bf16*  ZT = (bf16*)alloc((size_t)CHcap * MP * 2);       // 8 or 32 MB
    bf16*  E  = (bf16*)alloc((size_t)MP * MP * 2);          // 32 MB
    bf16*  Ab = useAB ? (bf16*)alloc((size_t)MP * MP * 2) : nullptr;  // 32 MB A-cache
    // XT = pad(X^T) bf16 (NP x NP, 18 MB) aliases E: consumed by layer-0
    // gemm1 before e_pass (first writer of E) runs.
    bf16* XT = E;

    // split-K slice count for contraction length Kc: only for small grids
    // (base < 192 blocks); want grid >= ~768; slice >= 256 K-elems.
    auto pickS = [](int base, int Kc) -> int {
        if (base >= 192) return 1;
        const int steps = Kc / 32;
        int best = 1;
        for (int S = 1; S <= 16; S++) {
            if (steps % S) continue;
            if (Kc / S < 256) continue;
            if (base * S > 1536) break;
            best = S;
            if (base * S >= 768) break;
        }
        return best;
    };

    // ---- prep ----
    sniff_dtype<<<1, 256, 0, stream>>>((const unsigned int*)X, flag);
    for (int l = 0; l < 7; l++) {
        long tot = (long)fop[l] * fip[l];
        padcopy<<<dim3((unsigned)((tot + 255) / 256)), 256, 0, stream>>>(
            W[l], foR[l], fiR[l], Wp[l], fop[l], fip[l], flag);
        padcopy<<<dim3((fop[l] + 255) / 256), 256, 0, stream>>>(
            Wb[l], 1, foR[l], Bp[l], 1, fop[l], flag);
    }
    padcopy_T<<<dim3(NP / 32, NP / 32), 256, 0, stream>>>(X, N_CELLS, XT, NP, flag);
    if (useAB)   // encoder-phase A cache (NP x NP bf16)
        padcopy<<<dim3((NP * NP) / 256), 256, 0, stream>>>(
            A_enc, N_CELLS, N_CELLS, Ab, NP, NP, flag);

    // HoutB != null: intermediate -> split-K atomic into Hf (f32, ld=nBtot),
    // then f32->bf16 convert. HoutB == null: output layer -> direct f32
    // stores; d4-shape (base grid 256) uses S=2 atomic with pre-zero.
    auto layer = [&](const bf16* Hin, int l, const void* Araw, int nABpad,
                     int nReal, int nPad, bf16* HoutB, float* HoutF,
                     int ldOut, int mB, int nBtot) {
        const int K = fip[l], NO = fop[l];
        const int CH = NO > CHcap ? CHcap : NO;
        const int nch = NO / CH;
        // gemm1 (operand-swapped): ZT[o,i] = relu(sum_k W[o,k]*Hin[i,k]+b[o]).
        // WITH_SCORES fuses s/r accumulation into the epilogue.
        auto gemm1 = [&](int c, bool withScores) {
            int sB = foR[l] - c * CH;
            if (sB > CH) sB = CH;
            if (sB < 0) sB = 0;
            if (withScores)
                gemm_nt<true, false, false, true, bf16><<<dim3(nPad / 128, CH / 128), 256, 0, stream>>>(
                    Wp[l] + (size_t)c * CH * K, K, Hin, K, Bp[l] + c * CH, nullptr,
                    ZT, nPad, K, CH, nPad,
                    vt[l], vr[l], flag, c * CH, sB, sb, rb);
            else
                gemm_nt<true, false, false, false, bf16><<<dim3(nPad / 128, CH / 128), 256, 0, stream>>>(
                    Wp[l] + (size_t)c * CH * K, K, Hin, K, Bp[l] + c * CH, nullptr,
                    ZT, nPad, K, CH, nPad,
                    nullptr, nullptr, nullptr, 0, 0, nullptr, nullptr);
        };
        // pass A: zero scores (sb, rb, rsum contiguous) then gemm1+scores
        zero_f32<<<dim3(3 * MP / 256), 256, 0, stream>>>(sb, 3 * MP);
        for (int c = 0; c < nch; c++) gemm1(c, true);
        // full E + row sums (score biases folded in)
        if (useAB)
            e_pass_pair<true><<<dim3(nPad / 64, nPad / 64), 256, 0, stream>>>(
                Ab, nABpad, nReal, sb, rb, vtb[l], vrb[l], E, nPad, rsum, flag);
        else
            e_pass_pair<false><<<dim3(nPad / 64, nPad / 64), 256, 0, stream>>>(
                Araw, nReal, nReal, sb, rb, vtb[l], vrb[l], E, nPad, rsum, flag);
        // pass B: gemm2 (contraction = nPad E-columns), softmax scale folded
        // into the epilogue via rcp(rsum).
        if (HoutB)
            zero_f32v<<<2048, 256, 0, stream>>>((f32x4*)Hf, (long)nPad * nBtot / 4);
        for (int c = 0; c < nch; c++) {
            if (nch > 1) gemm1(c, false);   // ZT intact when nch==1
            int colBase = c * CH;
            int nB = nBtot - colBase;
            if (nB > CH) nB = CH;
            if (nB <= 0) continue;
            const int bx = CH / 128, by = nPad / 128;
            if (HoutB) {
                const int S = pickS(bx * by, nPad);
                gemm_nt<false, true, true, false, float><<<dim3(bx, by, S), 256, 0, stream>>>(
                    E, nPad, ZT, nPad, nullptr, rsum,
                    Hf + colBase, nBtot, nPad, nPad, nB,
                    nullptr, nullptr, nullptr, 0, 0, nullptr, nullptr);
            } else {
                // output layer: S=2 atomic only for the 1-block/CU shape
                const int S = (nch == 1 && bx * by == 256) ? 2 : 1;
                if (S == 2) {
                    zero_f32v<<<2048, 256, 0, stream>>>(
                        (f32x4*)HoutF, (long)mB * ldOut / 4);
                    gemm_nt<false, true, true, false, float><<<dim3(bx, by, S), 256, 0, stream>>>(
                        E, nPad, ZT, nPad, nullptr, rsum,
                        HoutF + colBase, ldOut, nPad, mB, nB,
                        nullptr, nullptr, nullptr, 0, 0, nullptr, nullptr);
                } else {
                    gemm_nt<false, true, false, false, float><<<dim3(bx, by), 256, 0, stream>>>(
                        E, nPad, ZT, nPad, nullptr, rsum,
                        HoutF + colBase, ldOut, nPad, mB, nB,
                        nullptr, nullptr, nullptr, 0, 0, nullptr, nullptr);
                }
            }
        }
        if (HoutB)
            f32_to_bf16_v4<<<2048, 256, 0, stream>>>(
                (const f32x4*)Hf, (bf16x4*)HoutB, (long)nPad * nBtot / 4);
    };

    // encoder (H0 = X^T staged as XT by padcopy_T)
    layer(XT,      0, A_enc, NP, N_CELLS, NP, H1, nullptr, 512, NP, 512);
    layer(H1,      1, A_enc, NP, N_CELLS, NP, H2, nullptr, 256, NP, 256);
    layer(H2,      2, A_enc, NP, N_CELLS, NP, H3, nullptr, 128, NP, 128);
    // decoder input D = concat([gG, H3^T], axis=1)^T
    build_D<<<dim3((MP * 128) / 256), 256, 0, stream>>>(gG, H3, Dd, flag);
    if (useAB)   // decoder-phase A cache (MP x MP bf16, overwrites enc cache)
        padcopy<<<dim3((int)(((long)MP * MP) / 256)), 256, 0, stream>>>(
            A_dec, M_NODES, M_NODES, Ab, MP, MP, flag);
    layer(Dd, 3, A_dec, MP, M_NODES, MP, D1, nullptr, 256, MP, 256);
    layer(D1, 4, A_dec, MP, M_NODES, MP, D2, nullptr, 512, MP, 512);
    // outputs are float32 (reference dtype)
    float* outCell = (float*)d_out;
    float* outGene = outCell + (size_t)M_NODES * M_NODES;
    layer(D2, 5, A_dec, MP, M_NODES, MP, nullptr, outCell, 4000, 4000, 4000);
    layer(D2, 6, A_dec, MP, M_NODES, MP, nullptr, outGene, 1000, 4000, 1000);
}

// Round 9
// 1207.775 us; speedup vs baseline: 2.1067x; 1.0337x over previous
//
#include <hip/hip_runtime.h>
#include <hip/hip_bf16.h>

using bf16 = __hip_bfloat16;
typedef __bf16 bf16x8 __attribute__((ext_vector_type(8)));
typedef __bf16 bf16x4 __attribute__((ext_vector_type(4)));
typedef float f32x4 __attribute__((ext_vector_type(4)));
typedef unsigned short u16x4 __attribute__((ext_vector_type(4)));

#define N_CELLS 3000
#define N_GENES 1000
#define M_NODES 4000
#define NP 3072
#define MP 4096

// dual-mode scalar read: inputs are f32 (sniffed) or bf16 (hedge)
__device__ __forceinline__ float rdv(const void* p, size_t i, int isbf) {
    if (isbf) return (float)((const bf16*)p)[i];
    return ((const float*)p)[i];
}

// guarded 4-wide row load from dual-mode matrix (n x n), zero-padded
__device__ __forceinline__ f32x4 load4g(const void* A, int n, int row, int col, int isbf) {
    f32x4 v = {0.f, 0.f, 0.f, 0.f};
    if (row < n) {
        if (col + 3 < n) {
            if (isbf) {
                const u16x4 u = *(const u16x4*)((const unsigned short*)A + (size_t)row * n + col);
                #pragma unroll
                for (int k = 0; k < 4; k++) v[k] = __uint_as_float(((unsigned)u[k]) << 16);
            } else {
                v = *(const f32x4*)((const float*)A + (size_t)row * n + col);
            }
        } else {
            #pragma unroll
            for (int k = 0; k < 4; k++)
                if (col + k < n) v[k] = rdv(A, (size_t)row * n + col + k, isbf);
        }
    }
    return v;
}

// unguarded 4-wide load from padded bf16 matrix (stride ld)
__device__ __forceinline__ f32x4 load4b(const bf16* A, int ld, int row, int col) {
    const u16x4 u = *(const u16x4*)((const unsigned short*)A + (size_t)row * ld + col);
    f32x4 v;
    #pragma unroll
    for (int k = 0; k < 4; k++) v[k] = __uint_as_float(((unsigned)u[k]) << 16);
    return v;
}

__device__ __forceinline__ void async_copy16(const bf16* g, bf16* l) {
    __builtin_amdgcn_global_load_lds((const __attribute__((address_space(1))) void*)g,
                                     (__attribute__((address_space(3))) void*)l,
                                     16, 0, 0);
}

// X ~ U[0,1): as bf16 every word's low16 < 0x3F80 (~100%); as f32 ~25%.
__global__ void sniff_dtype(const unsigned int* __restrict__ X, int* __restrict__ flag)
{
    __shared__ int cnt[4];
    int t = threadIdx.x;
    int c = 0;
    for (int i = t; i < 2048; i += 256)
        if ((X[i] & 0xFFFFu) < 0x3F80u) c++;
    #pragma unroll
    for (int off = 32; off > 0; off >>= 1) c += __shfl_down(c, off);
    if ((t & 63) == 0) cnt[t >> 6] = c;
    __syncthreads();
    if (t == 0) flag[0] = (cnt[0] + cnt[1] + cnt[2] + cnt[3] > 1536) ? 1 : 0;
}

// ---------------------------------------------------------------------------
// NT GEMM, double-buffered async global->LDS staging, optional SPLIT-K:
// C[i,j] = sum_k A[i,k]*B[j,k], 128x128 tile, K%32==0, bf16 in, OutT out.
// BIAS_ROW: C = relu(C + bias[i]). SCALE_ROW: C *= rcp(rsum[i]) (pad rows->0).
// ATOMIC: atomicAdd f32 partials (dest pre-zeroed), gridDim.z = K slices.
// SCORES (gemm1 fusion): sAcc[j] += sum_i C[i,j]*vt[oBase+i] (i<oBound),
// rAcc likewise — per-column partials reduced via shfl, one atomic/col/wave.
// XCD swizzle: rectangular 8x16 per-XCD chunks for 32x32 grids, else m204.
// ---------------------------------------------------------------------------
template<bool BIAS_ROW, bool SCALE_ROW, bool ATOMIC, bool SCORES, typename OutT>
__global__ __launch_bounds__(256, 2)
void gemm_nt(const bf16* __restrict__ A, int lda,
             const bf16* __restrict__ B, int ldb,
             const bf16* __restrict__ bias,
             const float* __restrict__ rsum,
             OutT* __restrict__ C, int ldc,
             int K, int mBound, int nBound,
             const void* __restrict__ vtp, const void* __restrict__ vrp,
             const int* __restrict__ flag, int oBase, int oBound,
             float* __restrict__ sAcc, float* __restrict__ rAcc)
{
    __shared__ __align__(16) bf16 As[2][128 * 32];
    __shared__ __align__(16) bf16 Bs[2][128 * 32];
    const int tid  = threadIdx.x;
    const int wave = tid >> 6;
    const int lane = tid & 63;

    const int orig = blockIdx.y * gridDim.x + blockIdx.x;
    int i0, j0;
    if (gridDim.x == 32 && gridDim.y == 32) {
        // rectangular per-XCD chunk: XCD owns an 8-row x 16-col tile rect
        const int xcd = orig & 7, idx = orig >> 3;
        const int r = ((xcd >> 1) << 3) + (idx >> 4);
        const int c = ((xcd & 1) << 4) + (idx & 15);
        i0 = r * 128;
        j0 = c * 128;
    } else {
        // bijective XCD swizzle (m204)
        const int nwg = gridDim.x * gridDim.y;
        const int q = nwg >> 3, rr = nwg & 7;
        const int xcd = orig & 7, idx = orig >> 3;
        const int swz = (xcd < rr ? xcd * (q + 1) : rr * (q + 1) + (xcd - rr) * q) + idx;
        i0 = (swz / gridDim.x) * 128;
        j0 = (swz % gridDim.x) * 128;
    }

    // split-K slice
    const int kSlice = K / gridDim.z;
    const int kBase  = blockIdx.z * kSlice;
    const int kEnd   = kBase + kSlice;

    // async staging: wave w covers rows [w*32, w*32+32); lane -> (srow, 8-elem k)
    const int srow = lane >> 2;          // 0..15
    const int sk   = (lane & 3) * 8;     // 0,8,16,24
    const bf16* gA0 = A + (size_t)(i0 + wave * 32 + srow) * lda + sk;
    const bf16* gA1 = gA0 + (size_t)16 * lda;
    const bf16* gB0 = B + (size_t)(j0 + wave * 32 + srow) * ldb + sk;
    const bf16* gB1 = gB0 + (size_t)16 * ldb;
    const int loA0 = (wave * 32) * 32;
    const int loA1 = (wave * 32 + 16) * 32;

    const int wm = (wave >> 1) * 64;
    const int wn = (wave & 1) * 64;
    const int fr = lane & 15;
    const int fk = (lane >> 4) * 8;

    f32x4 acc[4][4] = {};

    auto stage = [&](int buf, int kt) {
        async_copy16(gA0 + kt, &As[buf][loA0]);
        async_copy16(gA1 + kt, &As[buf][loA1]);
        async_copy16(gB0 + kt, &Bs[buf][loA0]);
        async_copy16(gB1 + kt, &Bs[buf][loA1]);
    };

    stage(0, kBase);
    __syncthreads();             // prologue drain (once)
    int cur = 0;

    for (int kt = kBase; kt < kEnd; kt += 32) {
        if (kt + 32 < kEnd) stage(cur ^ 1, kt + 32);   // prefetch next tile

        bf16x8 af[4], bfv[4];
        #pragma unroll
        for (int t = 0; t < 4; t++) {
            af[t]  = *(const bf16x8*)&As[cur][(wm + t * 16 + fr) * 32 + fk];
            bfv[t] = *(const bf16x8*)&Bs[cur][(wn + t * 16 + fr) * 32 + fk];
        }
        #pragma unroll
        for (int mt = 0; mt < 4; mt++)
            #pragma unroll
            for (int nt = 0; nt < 4; nt++)
                acc[mt][nt] = __builtin_amdgcn_mfma_f32_16x16x32_bf16(
                    af[mt], bfv[nt], acc[mt][nt], 0, 0, 0);

        __syncthreads();   // prefetch landed; reads done -> safe to flip
        cur ^= 1;
    }

    // C/D mapping: col(n)=lane&15, row(m)=(lane>>4)*4+reg
    const int ci = (lane >> 4) * 4;
    const int cj = lane & 15;
    int isbf = 0;
    if constexpr (SCORES) isbf = flag[0];
    float ps[4] = {0.f, 0.f, 0.f, 0.f};
    float pr[4] = {0.f, 0.f, 0.f, 0.f};
    #pragma unroll
    for (int mt = 0; mt < 4; mt++) {
        #pragma unroll
        for (int rg = 0; rg < 4; rg++) {
            const int gi = i0 + wm + mt * 16 + ci + rg;
            if (gi >= mBound) continue;
            float bv = 0.f, rc = 1.f;
            if (BIAS_ROW) bv = (float)bias[gi];
            if (SCALE_ROW) {
                const float r_ = rsum[gi];
                rc = r_ > 0.f ? __builtin_amdgcn_rcpf(r_) : 0.f;
            }
            float vtv = 0.f, vrv = 0.f;
            if constexpr (SCORES) {
                if (gi < oBound) {
                    vtv = rdv(vtp, (size_t)(oBase + gi), isbf);
                    vrv = rdv(vrp, (size_t)(oBase + gi), isbf);
                }
            }
            #pragma unroll
            for (int nt = 0; nt < 4; nt++) {
                const int gj = j0 + wn + nt * 16 + cj;
                if (gj >= nBound) continue;
                float v = acc[mt][nt][rg];
                if (BIAS_ROW) { v += bv; v = v > 0.f ? v : 0.f; }
                if (SCALE_ROW) v *= rc;
                if constexpr (ATOMIC) {
                    atomicAdd((float*)&C[(size_t)gi * ldc + gj], v);
                } else {
                    C[(size_t)gi * ldc + gj] = (OutT)v;
                }
                if constexpr (SCORES) {
                    ps[nt] += v * vtv;
                    pr[nt] += v * vrv;
                }
            }
        }
    }
    if constexpr (SCORES) {
        // lanes sharing a column are 16 apart: reduce 4 -> lane<16
        #pragma unroll
        for (int nt = 0; nt < 4; nt++) {
            float p = ps[nt], r2 = pr[nt];
            p  += __shfl_down(p, 32);  p  += __shfl_down(p, 16);
            r2 += __shfl_down(r2, 32); r2 += __shfl_down(r2, 16);
            if (lane < 16) {
                const int gj = j0 + wn + nt * 16 + lane;
                if (gj < nBound) {
                    atomicAdd(&sAcc[gj], p);
                    atomicAdd(&rAcc[gj], r2);
                }
            }
        }
    }
}

// dst (rp x cp) bf16 = src (r x c, dual-mode) zero-padded
__global__ void padcopy(const void* __restrict__ src, int r, int c,
                        bf16* __restrict__ dst, int rp, int cp,
                        const int* __restrict__ flag)
{
    const int isbf = flag[0];
    long idx = (long)blockIdx.x * 256 + threadIdx.x;
    if (idx >= (long)rp * cp) return;
    int i = (int)(idx / cp), j = (int)(idx % cp);
    float v = 0.f;
    if (i < r && j < c) v = rdv(src, (size_t)i * c + j, isbf);
    dst[idx] = (bf16)v;
}

// fused multi-segment padcopy: 14 weight/bias segments in one grid-stride
// launch (replaces 14 tiny dispatches). Segment found by unrolled scan.
struct PadSeg { const void* src; bf16* dst; int r, c, cp; long base; };
struct PadArgs { PadSeg seg[14]; long total; };
__global__ void padcopy_multi(PadArgs a, const int* __restrict__ flag)
{
    const int isbf = flag[0];
    long idx = (long)blockIdx.x * 256 + threadIdx.x;
    const long str = (long)gridDim.x * 256;
    for (; idx < a.total; idx += str) {
        int s = 0;
        #pragma unroll
        for (int k = 1; k < 14; k++) if (idx >= a.seg[k].base) s = k;
        const long loc = idx - a.seg[s].base;
        const int cp = a.seg[s].cp;
        const int i = (int)(loc / cp), j = (int)(loc % cp);
        float v = 0.f;
        if (i < a.seg[s].r && j < a.seg[s].c)
            v = rdv(a.seg[s].src, (size_t)i * a.seg[s].c + j, isbf);
        a.seg[s].dst[loc] = (bf16)v;
    }
}

// XT (np x np bf16) = transpose of src (n x n, dual-mode), zero-padded.
__global__ void padcopy_T(const void* __restrict__ src, int n,
                          bf16* __restrict__ dst, int np,
                          const int* __restrict__ flag)
{
    __shared__ float t[32][33];
    const int isbf = flag[0];
    const int tx = threadIdx.x & 31;
    const int ty = threadIdx.x >> 5;     // 0..7
    const int i0 = blockIdx.y * 32;      // output row block (i = src col)
    const int k0 = blockIdx.x * 32;      // output col block (k = src row)
    #pragma unroll
    for (int q = 0; q < 4; q++) {        // stage src[k0+r][i0+tx]
        int k = k0 + ty + q * 8;
        float v = 0.f;
        if (k < n && i0 + tx < n) v = rdv(src, (size_t)k * n + i0 + tx, isbf);
        t[ty + q * 8][tx] = v;
    }
    __syncthreads();
    #pragma unroll
    for (int q = 0; q < 4; q++) {        // write dst[i0+r][k0+tx] = src[k0+tx][i0+r]
        int i = ty + q * 8;
        dst[(size_t)(i0 + i) * np + k0 + tx] = (bf16)t[tx][i];
    }
}

__global__ void zero_f32(float* __restrict__ p, int n)
{
    int i = blockIdx.x * 256 + threadIdx.x;
    if (i < n) p[i] = 0.f;
}

// grid-stride vectorized zero (n4 = count of float4)
__global__ void zero_f32v(f32x4* __restrict__ p, long n4)
{
    long i = (long)blockIdx.x * 256 + threadIdx.x;
    const long str = (long)gridDim.x * 256;
    const f32x4 z = {0.f, 0.f, 0.f, 0.f};
    for (; i < n4; i += str) p[i] = z;
}

// grid-stride vectorized f32 -> bf16 convert (n4 = count of 4-elem groups)
__global__ void f32_to_bf16_v4(const f32x4* __restrict__ src, bf16x4* __restrict__ dst, long n4)
{
    long i = (long)blockIdx.x * 256 + threadIdx.x;
    const long str = (long)gridDim.x * 256;
    for (; i < n4; i += str) {
        f32x4 v = src[i];
        bf16x4 w;
        #pragma unroll
        for (int k = 0; k < 4; k++) w[k] = (__bf16)v[k];
        dst[i] = w;
    }
}

// ---------------------------------------------------------------------------
// Paired E-pass: block (bi<=bj) computes E tiles (I,J) and (J,I), 64x64 each.
// E[i,j] = exp(sigmoid(A[i,j]*(s[j]+vtb) + A[j,i]*(r[i]+vrb))), i,j<n else 0.
// CB=true: A is padded bf16 (stride ldA); transposes staged as bf16 in dynamic
// LDS [2][64][66] (16.9KB -> 8 blocks/CU; stride 66 = 33 dwords == 1 mod 32 ->
// conflict-free reads along rows). CB=false: raw dual-mode A, f32 LDS
// [2][64][65] (33.3KB, exact prior behavior).
// ---------------------------------------------------------------------------
template<bool CB>
__global__ __launch_bounds__(256)
void e_pass_pair(const void* __restrict__ A, int ldA, int n,
                 const float* __restrict__ s, const float* __restrict__ r,
                 const void* __restrict__ vtb, const void* __restrict__ vrb,
                 bf16* __restrict__ E, int ldE, float* __restrict__ rowsum,
                 const int* __restrict__ flag)
{
    extern __shared__ char smem[];
    const int bi = blockIdx.y, bj = blockIdx.x;
    if (bj < bi) return;
    const int isbf = flag[0];
    const int tid = threadIdx.x;
    const int i0 = bi * 64, j0 = bj * 64;
    const int tx = tid & 15;         // col group: 4 consecutive cols
    const int ty = tid >> 4;         // 0..15
    const int c0 = 4 * tx;
    const float bt = rdv(vtb, 0, isbf);
    const float br = rdv(vrb, 0, isbf);

    auto ld4 = [&](int row, int col) -> f32x4 {
        if constexpr (CB) return load4b((const bf16*)A, ldA, row, col);
        else              return load4g(A, n, row, col, isbf);
    };
    // T[which][a][b]: which=0 -> T1t[a][b]=A[i0+b][j0+a]; which=1 -> T2t
    auto stT = [&](int which, int a, int b, float v) {
        if constexpr (CB) ((__bf16*)smem)[((which << 6) + a) * 66 + b] = (__bf16)v;
        else              ((float*)smem)[((which << 6) + a) * 65 + b] = v;
    };
    auto ldT = [&](int which, int a, int b) -> float {
        if constexpr (CB) return (float)((__bf16*)smem)[((which << 6) + a) * 66 + b];
        else              return ((float*)smem)[((which << 6) + a) * 65 + b];
    };

    #pragma unroll
    for (int rr = 0; rr < 4; rr++) {
        const int rw = ty + 16 * rr;                       // 0..63
        f32x4 v1 = ld4(i0 + rw, j0 + c0);                  // region1 row
        f32x4 v2 = ld4(j0 + rw, i0 + c0);                  // region2 row
        #pragma unroll
        for (int k = 0; k < 4; k++) {
            stT(0, c0 + k, rw, v1[k]);
            stT(1, c0 + k, rw, v2[k]);
        }
    }
    __syncthreads();

    const float LOG2E = 1.442695041f;

    // ---- tile1: rows I, cols J ----
    {
        f32x4 s4 = *(const f32x4*)&s[j0 + c0];
        #pragma unroll
        for (int k = 0; k < 4; k++) s4[k] += bt;
        #pragma unroll
        for (int q = 0; q < 4; q++) {
            const int li = ty + 16 * q;
            const int gi = i0 + li;
            const float rv = r[gi] + br;
            const f32x4 a = ld4(gi, j0 + c0);
            f32x4 ev;
            float part = 0.f;
            #pragma unroll
            for (int k = 0; k < 4; k++) {
                const float trn = ldT(1, li, c0 + k);          // A[gj][gi]
                const float x = a[k] * s4[k] + trn * rv;
                const float t = __builtin_amdgcn_exp2f(-x * LOG2E);
                const float sig = __builtin_amdgcn_rcpf(1.f + t);
                float e = __builtin_amdgcn_exp2f(sig * LOG2E);
                const int gj = j0 + c0 + k;
                e = (gi < n && gj < n) ? e : 0.f;
                ev[k] = e;
                part += e;
            }
            bf16x4 w;
            #pragma unroll
            for (int k = 0; k < 4; k++) w[k] = (__bf16)ev[k];
            *(bf16x4*)&E[(size_t)gi * ldE + j0 + c0] = w;
            part += __shfl_down(part, 8, 16);
            part += __shfl_down(part, 4, 16);
            part += __shfl_down(part, 2, 16);
            part += __shfl_down(part, 1, 16);
            if (tx == 0) atomicAdd(&rowsum[gi], part);
        }
    }

    // ---- tile2: rows J, cols I (skip on diagonal) ----
    if (bj > bi) {
        f32x4 s4 = *(const f32x4*)&s[i0 + c0];
        #pragma unroll
        for (int k = 0; k < 4; k++) s4[k] += bt;
        #pragma unroll
        for (int q = 0; q < 4; q++) {
            const int lr = ty + 16 * q;
            const int gr = j0 + lr;
            const float rv = r[gr] + br;
            const f32x4 a = ld4(gr, i0 + c0);
            f32x4 ev;
            float part = 0.f;
            #pragma unroll
            for (int k = 0; k < 4; k++) {
                const float trn = ldT(0, lr, c0 + k);          // A[gj][gr]
                const float x = a[k] * s4[k] + trn * rv;
                const float t = __builtin_amdgcn_exp2f(-x * LOG2E);
                const float sig = __builtin_amdgcn_rcpf(1.f + t);
                float e = __builtin_amdgcn_exp2f(sig * LOG2E);
                const int gj = i0 + c0 + k;
                e = (gr < n && gj < n) ? e : 0.f;
                ev[k] = e;
                part += e;
            }
            bf16x4 w;
            #pragma unroll
            for (int k = 0; k < 4; k++) w[k] = (__bf16)ev[k];
            *(bf16x4*)&E[(size_t)gr * ldE + i0 + c0] = w;
            part += __shfl_down(part, 8, 16);
            part += __shfl_down(part, 4, 16);
            part += __shfl_down(part, 2, 16);
            part += __shfl_down(part, 1, 16);
            if (tx == 0) atomicAdd(&rowsum[gr], part);
        }
    }
}

// D (MP x 128): rows m<G from gG[c,m] (dual); rows G..M-1 from H3[m-G,c]; else 0
__global__ void build_D(const void* __restrict__ gG, const bf16* __restrict__ H3,
                        bf16* __restrict__ D, const int* __restrict__ flag)
{
    const int isbf = flag[0];
    int idx = blockIdx.x * 256 + threadIdx.x;
    int m = idx >> 7, c = idx & 127;
    float v = 0.f;
    if (c < 64) {
        if (m < N_GENES)      v = rdv(gG, (size_t)c * N_GENES + m, isbf);
        else if (m < M_NODES) v = (float)H3[(size_t)(m - N_GENES) * 128 + c];
    }
    D[idx] = (bf16)v;
}

extern "C" void kernel_launch(void* const* d_in, const int* in_sizes, int n_in,
                              void* d_out, int out_size, void* d_ws, size_t ws_size,
                              hipStream_t stream)
{
    const void* X     = d_in[0];
    const void* A_enc = d_in[1];
    const void* A_dec = d_in[2];
    const void* gG    = d_in[3];
    const void *W[7], *Wb[7], *vt[7], *vtb[7], *vr[7], *vrb[7];
    for (int l = 0; l < 7; l++) {
        W[l]   = d_in[4 + 6 * l + 0];
        Wb[l]  = d_in[4 + 6 * l + 1];
        vt[l]  = d_in[4 + 6 * l + 2];
        vtb[l] = d_in[4 + 6 * l + 3];
        vr[l]  = d_in[4 + 6 * l + 4];
        vrb[l] = d_in[4 + 6 * l + 5];
    }

    const int fop[7] = {512, 256, 128, 256, 512, 4096, 1024};
    const int fip[7] = {3072, 512, 256, 128, 256, 512, 512};
    const int foR[7] = {512, 256, 64, 256, 512, 4000, 1000};
    const int fiR[7] = {3000, 512, 256, 64, 256, 512, 512};

    // gates: full-Z ZT (32 MB) at ws>=100 MB; bf16 A-cache (+32 MB) at >=130.
    const int  CHcap = (ws_size >= (size_t)100 * 1024 * 1024) ? 4096 : 1024;
    const bool useAB = (ws_size >= (size_t)130 * 1024 * 1024);

    // ---- workspace layout, small first ----
    char* ws = (char*)d_ws;
    size_t off = 0;
    auto alloc = [&](size_t bytes) -> void* {
        void* p = ws + off;
        off += (bytes + 255) & ~(size_t)255;
        return p;
    };
    int*   flag = (int*)alloc(256);
    float* sb   = (float*)alloc((size_t)MP * 4);   // sb, rb, rsum contiguous
    float* rb   = (float*)alloc((size_t)MP * 4);
    float* rsum = (float*)alloc((size_t)MP * 4);
    bf16* Bp[7];
    for (int l = 0; l < 7; l++) Bp[l] = (bf16*)alloc((size_t)fop[l] * 2);
    bf16* RA = (bf16*)alloc((size_t)NP * 512 * 2);   // H1 -> H3 -> D1
    bf16* RB = (bf16*)alloc((size_t)NP * 256 * 2);   // H2 -> Dd
    bf16* RC = (bf16*)alloc((size_t)MP * 512 * 2);   // D2
    bf16 *H1 = RA, *H3 = RA, *D1 = RA;
    bf16 *H2 = RB, *Dd = RB;
    bf16 *D2 = RC;
    bf16* Wp[7];
    for (int l = 0; l < 7; l++) Wp[l] = (bf16*)alloc((size_t)fop[l] * fip[l] * 2);
    float* Hf = (float*)alloc((size_t)MP * 512 * 4);        // 8 MB split-K f32 accum
    bf16*  ZT = (bf16*)alloc((size_t)CHcap * MP * 2);       // 8 or 32 MB
    bf16*  E  = (bf16*)alloc((size_t)MP * MP * 2);          // 32 MB
    bf16*  Ab = useAB ? (bf16*)alloc((size_t)MP * MP * 2) : nullptr;  // 32 MB A-cache
    // XT = pad(X^T) bf16 (NP x NP, 18 MB) aliases E: consumed by layer-0
    // gemm1 before e_pass (first writer of E) runs.
    bf16* XT = E;

    // split-K slice count for contraction length Kc: only for small grids
    // (base < 192 blocks); want grid >= ~768; slice >= 256 K-elems.
    auto pickS = [](int base, int Kc) -> int {
        if (base >= 192) return 1;
        const int steps = Kc / 32;
        int best = 1;
        for (int S = 1; S <= 16; S++) {
            if (steps % S) continue;
            if (Kc / S < 256) continue;
            if (base * S > 1536) break;
            best = S;
            if (base * S >= 768) break;
        }
        return best;
    };

    // ---- prep ----
    sniff_dtype<<<1, 256, 0, stream>>>((const unsigned int*)X, flag);
    {
        PadArgs pa;
        long base = 0;
        for (int l = 0; l < 7; l++) {
            pa.seg[l] = {W[l], Wp[l], foR[l], fiR[l], fip[l], base};
            base += (long)fop[l] * fip[l];
        }
        for (int l = 0; l < 7; l++) {
            pa.seg[7 + l] = {Wb[l], Bp[l], 1, foR[l], fop[l], base};
            base += fop[l];
        }
        pa.total = base;
        padcopy_multi<<<2048, 256, 0, stream>>>(pa, flag);
    }
    padcopy_T<<<dim3(NP / 32, NP / 32), 256, 0, stream>>>(X, N_CELLS, XT, NP, flag);
    if (useAB)   // encoder-phase A cache (NP x NP bf16)
        padcopy<<<dim3((NP * NP) / 256), 256, 0, stream>>>(
            A_enc, N_CELLS, N_CELLS, Ab, NP, NP, flag);

    const unsigned smemCB = 2 * 64 * 66 * 2;        // bf16 path
    const unsigned smemF  = 2 * 64 * 65 * 4;        // f32 fallback

    // HoutB != null: intermediate -> split-K atomic into Hf (f32, ld=nBtot),
    // then f32->bf16 convert. HoutB == null: output layer -> direct f32
    // stores; d4-shape (base grid 256) uses S=2 atomic with pre-zero.
    auto layer = [&](const bf16* Hin, int l, const void* Araw, int nABpad,
                     int nReal, int nPad, bf16* HoutB, float* HoutF,
                     int ldOut, int mB, int nBtot) {
        const int K = fip[l], NO = fop[l];
        const int CH = NO > CHcap ? CHcap : NO;
        const int nch = NO / CH;
        // gemm1 (operand-swapped): ZT[o,i] = relu(sum_k W[o,k]*Hin[i,k]+b[o]).
        // WITH_SCORES fuses s/r accumulation into the epilogue.
        auto gemm1 = [&](int c, bool withScores) {
            int sB = foR[l] - c * CH;
            if (sB > CH) sB = CH;
            if (sB < 0) sB = 0;
            if (withScores)
                gemm_nt<true, false, false, true, bf16><<<dim3(nPad / 128, CH / 128), 256, 0, stream>>>(
                    Wp[l] + (size_t)c * CH * K, K, Hin, K, Bp[l] + c * CH, nullptr,
                    ZT, nPad, K, CH, nPad,
                    vt[l], vr[l], flag, c * CH, sB, sb, rb);
            else
                gemm_nt<true, false, false, false, bf16><<<dim3(nPad / 128, CH / 128), 256, 0, stream>>>(
                    Wp[l] + (size_t)c * CH * K, K, Hin, K, Bp[l] + c * CH, nullptr,
                    ZT, nPad, K, CH, nPad,
                    nullptr, nullptr, nullptr, 0, 0, nullptr, nullptr);
        };
        // pass A: zero scores (sb, rb, rsum contiguous) then gemm1+scores
        zero_f32<<<dim3(3 * MP / 256), 256, 0, stream>>>(sb, 3 * MP);
        for (int c = 0; c < nch; c++) gemm1(c, true);
        // full E + row sums (score biases folded in)
        if (useAB)
            e_pass_pair<true><<<dim3(nPad / 64, nPad / 64), 256, smemCB, stream>>>(
                Ab, nABpad, nReal, sb, rb, vtb[l], vrb[l], E, nPad, rsum, flag);
        else
            e_pass_pair<false><<<dim3(nPad / 64, nPad / 64), 256, smemF, stream>>>(
                Araw, nReal, nReal, sb, rb, vtb[l], vrb[l], E, nPad, rsum, flag);
        // pass B: gemm2 (contraction = nPad E-columns), softmax scale folded
        // into the epilogue via rcp(rsum).
        if (HoutB)
            zero_f32v<<<2048, 256, 0, stream>>>((f32x4*)Hf, (long)nPad * nBtot / 4);
        for (int c = 0; c < nch; c++) {
            if (nch > 1) gemm1(c, false);   // ZT intact when nch==1
            int colBase = c * CH;
            int nB = nBtot - colBase;
            if (nB > CH) nB = CH;
            if (nB <= 0) continue;
            const int bx = CH / 128, by = nPad / 128;
            if (HoutB) {
                const int S = pickS(bx * by, nPad);
                gemm_nt<false, true, true, false, float><<<dim3(bx, by, S), 256, 0, stream>>>(
                    E, nPad, ZT, nPad, nullptr, rsum,
                    Hf + colBase, nBtot, nPad, nPad, nB,
                    nullptr, nullptr, nullptr, 0, 0, nullptr, nullptr);
            } else {
                // output layer: S=2 atomic only for the 1-block/CU shape
                const int S = (nch == 1 && bx * by == 256) ? 2 : 1;
                if (S == 2) {
                    zero_f32v<<<2048, 256, 0, stream>>>(
                        (f32x4*)HoutF, (long)mB * ldOut / 4);
                    gemm_nt<false, true, true, false, float><<<dim3(bx, by, S), 256, 0, stream>>>(
                        E, nPad, ZT, nPad, nullptr, rsum,
                        HoutF + colBase, ldOut, nPad, mB, nB,
                        nullptr, nullptr, nullptr, 0, 0, nullptr, nullptr);
                } else {
                    gemm_nt<false, true, false, false, float><<<dim3(bx, by), 256, 0, stream>>>(
                        E, nPad, ZT, nPad, nullptr, rsum,
                        HoutF + colBase, ldOut, nPad, mB, nB,
                        nullptr, nullptr, nullptr, 0, 0, nullptr, nullptr);
                }
            }
        }
        if (HoutB)
            f32_to_bf16_v4<<<2048, 256, 0, stream>>>(
                (const f32x4*)Hf, (bf16x4*)HoutB, (long)nPad * nBtot / 4);
    };

    // encoder (H0 = X^T staged as XT by padcopy_T)
    layer(XT,      0, A_enc, NP, N_CELLS, NP, H1, nullptr, 512, NP, 512);
    layer(H1,      1, A_enc, NP, N_CELLS, NP, H2, nullptr, 256, NP, 256);
    layer(H2,      2, A_enc, NP, N_CELLS, NP, H3, nullptr, 128, NP, 128);
    // decoder input D = concat([gG, H3^T], axis=1)^T
    build_D<<<dim3((MP * 128) / 256), 256, 0, stream>>>(gG, H3, Dd, flag);
    if (useAB)   // decoder-phase A cache (MP x MP bf16, overwrites enc cache)
        padcopy<<<dim3((int)(((long)MP * MP) / 256)), 256, 0, stream>>>(
            A_dec, M_NODES, M_NODES, Ab, MP, MP, flag);
    layer(Dd, 3, A_dec, MP, M_NODES, MP, D1, nullptr, 256, MP, 256);
    layer(D1, 4, A_dec, MP, M_NODES, MP, D2, nullptr, 512, MP, 512);
    // outputs are float32 (reference dtype)
    float* outCell = (float*)d_out;
    float* outGene = outCell + (size_t)M_NODES * M_NODES;
    layer(D2, 5, A_dec, MP, M_NODES, MP, nullptr, outCell, 4000, 4000, 4000);
    layer(D2, 6, A_dec, MP, M_NODES, MP, nullptr, outGene, 1000, 4000, 1000);
}

// Round 10
// 1081.534 us; speedup vs baseline: 2.3526x; 1.1167x over previous
//
#include <hip/hip_runtime.h>
#include <hip/hip_bf16.h>

using bf16 = __hip_bfloat16;
typedef __bf16 bf16x8 __attribute__((ext_vector_type(8)));
typedef __bf16 bf16x4 __attribute__((ext_vector_type(4)));
typedef float f32x4 __attribute__((ext_vector_type(4)));
typedef unsigned short u16x4 __attribute__((ext_vector_type(4)));

#define N_CELLS 3000
#define N_GENES 1000
#define M_NODES 4000
#define NP 3072
#define MP 4096

// dual-mode scalar read: inputs are f32 (sniffed) or bf16 (hedge)
__device__ __forceinline__ float rdv(const void* p, size_t i, int isbf) {
    if (isbf) return (float)((const bf16*)p)[i];
    return ((const float*)p)[i];
}

// guarded 4-wide row load from dual-mode matrix (n x n), zero-padded
__device__ __forceinline__ f32x4 load4g(const void* A, int n, int row, int col, int isbf) {
    f32x4 v = {0.f, 0.f, 0.f, 0.f};
    if (row < n) {
        if (col + 3 < n) {
            if (isbf) {
                const u16x4 u = *(const u16x4*)((const unsigned short*)A + (size_t)row * n + col);
                #pragma unroll
                for (int k = 0; k < 4; k++) v[k] = __uint_as_float(((unsigned)u[k]) << 16);
            } else {
                v = *(const f32x4*)((const float*)A + (size_t)row * n + col);
            }
        } else {
            #pragma unroll
            for (int k = 0; k < 4; k++)
                if (col + k < n) v[k] = rdv(A, (size_t)row * n + col + k, isbf);
        }
    }
    return v;
}

// unguarded 4-wide load from padded bf16 matrix (stride ld)
__device__ __forceinline__ f32x4 load4b(const bf16* A, int ld, int row, int col) {
    const u16x4 u = *(const u16x4*)((const unsigned short*)A + (size_t)row * ld + col);
    f32x4 v;
    #pragma unroll
    for (int k = 0; k < 4; k++) v[k] = __uint_as_float(((unsigned)u[k]) << 16);
    return v;
}

__device__ __forceinline__ void async_copy16(const bf16* g, bf16* l) {
    __builtin_amdgcn_global_load_lds((const __attribute__((address_space(1))) void*)g,
                                     (__attribute__((address_space(3))) void*)l,
                                     16, 0, 0);
}

// X ~ U[0,1): as bf16 every word's low16 < 0x3F80 (~100%); as f32 ~25%.
__global__ void sniff_dtype(const unsigned int* __restrict__ X, int* __restrict__ flag)
{
    __shared__ int cnt[4];
    int t = threadIdx.x;
    int c = 0;
    for (int i = t; i < 2048; i += 256)
        if ((X[i] & 0xFFFFu) < 0x3F80u) c++;
    #pragma unroll
    for (int off = 32; off > 0; off >>= 1) c += __shfl_down(c, off);
    if ((t & 63) == 0) cnt[t >> 6] = c;
    __syncthreads();
    if (t == 0) flag[0] = (cnt[0] + cnt[1] + cnt[2] + cnt[3] > 1536) ? 1 : 0;
}

// ---------------------------------------------------------------------------
// NT GEMM, double-buffered async global->LDS staging, optional SPLIT-K:
// C[i,j] = sum_k A[i,k]*B[j,k], 128x128 tile, K%32==0, bf16 in, OutT out.
// BIAS_ROW: C = relu(C + bias[i]). SCALE_ROW: C *= rcp(rsum[i]) (pad rows->0).
// ATOMIC: atomicAdd f32 partials (dest pre-zeroed), gridDim.z = K slices.
// SCORES (gemm1 fusion): sAcc[j] += sum_i C[i,j]*vt[oBase+i] (i<oBound).
// XCD swizzle: rectangular 8x16 per-XCD chunks for 32x32 grids, else m204.
// ---------------------------------------------------------------------------
template<bool BIAS_ROW, bool SCALE_ROW, bool ATOMIC, bool SCORES, typename OutT>
__global__ __launch_bounds__(256, 2)
void gemm_nt(const bf16* __restrict__ A, int lda,
             const bf16* __restrict__ B, int ldb,
             const bf16* __restrict__ bias,
             const float* __restrict__ rsum,
             OutT* __restrict__ C, int ldc,
             int K, int mBound, int nBound,
             const void* __restrict__ vtp, const void* __restrict__ vrp,
             const int* __restrict__ flag, int oBase, int oBound,
             float* __restrict__ sAcc, float* __restrict__ rAcc)
{
    __shared__ __align__(16) bf16 As[2][128 * 32];
    __shared__ __align__(16) bf16 Bs[2][128 * 32];
    const int tid  = threadIdx.x;
    const int wave = tid >> 6;
    const int lane = tid & 63;

    const int orig = blockIdx.y * gridDim.x + blockIdx.x;
    int i0, j0;
    if (gridDim.x == 32 && gridDim.y == 32) {
        // rectangular per-XCD chunk: XCD owns an 8-row x 16-col tile rect
        const int xcd = orig & 7, idx = orig >> 3;
        const int r = ((xcd >> 1) << 3) + (idx >> 4);
        const int c = ((xcd & 1) << 4) + (idx & 15);
        i0 = r * 128;
        j0 = c * 128;
    } else {
        // bijective XCD swizzle (m204)
        const int nwg = gridDim.x * gridDim.y;
        const int q = nwg >> 3, rr = nwg & 7;
        const int xcd = orig & 7, idx = orig >> 3;
        const int swz = (xcd < rr ? xcd * (q + 1) : rr * (q + 1) + (xcd - rr) * q) + idx;
        i0 = (swz / gridDim.x) * 128;
        j0 = (swz % gridDim.x) * 128;
    }

    // split-K slice
    const int kSlice = K / gridDim.z;
    const int kBase  = blockIdx.z * kSlice;
    const int kEnd   = kBase + kSlice;

    // async staging: wave w covers rows [w*32, w*32+32); lane -> (srow, 8-elem k)
    const int srow = lane >> 2;          // 0..15
    const int sk   = (lane & 3) * 8;     // 0,8,16,24
    const bf16* gA0 = A + (size_t)(i0 + wave * 32 + srow) * lda + sk;
    const bf16* gA1 = gA0 + (size_t)16 * lda;
    const bf16* gB0 = B + (size_t)(j0 + wave * 32 + srow) * ldb + sk;
    const bf16* gB1 = gB0 + (size_t)16 * ldb;
    const int loA0 = (wave * 32) * 32;
    const int loA1 = (wave * 32 + 16) * 32;

    const int wm = (wave >> 1) * 64;
    const int wn = (wave & 1) * 64;
    const int fr = lane & 15;
    const int fk = (lane >> 4) * 8;

    f32x4 acc[4][4] = {};

    auto stage = [&](int buf, int kt) {
        async_copy16(gA0 + kt, &As[buf][loA0]);
        async_copy16(gA1 + kt, &As[buf][loA1]);
        async_copy16(gB0 + kt, &Bs[buf][loA0]);
        async_copy16(gB1 + kt, &Bs[buf][loA1]);
    };

    stage(0, kBase);
    __syncthreads();             // prologue drain (once)
    int cur = 0;

    for (int kt = kBase; kt < kEnd; kt += 32) {
        if (kt + 32 < kEnd) stage(cur ^ 1, kt + 32);   // prefetch next tile

        bf16x8 af[4], bfv[4];
        #pragma unroll
        for (int t = 0; t < 4; t++) {
            af[t]  = *(const bf16x8*)&As[cur][(wm + t * 16 + fr) * 32 + fk];
            bfv[t] = *(const bf16x8*)&Bs[cur][(wn + t * 16 + fr) * 32 + fk];
        }
        #pragma unroll
        for (int mt = 0; mt < 4; mt++)
            #pragma unroll
            for (int nt = 0; nt < 4; nt++)
                acc[mt][nt] = __builtin_amdgcn_mfma_f32_16x16x32_bf16(
                    af[mt], bfv[nt], acc[mt][nt], 0, 0, 0);

        __syncthreads();   // prefetch landed; reads done -> safe to flip
        cur ^= 1;
    }

    // C/D mapping: col(n)=lane&15, row(m)=(lane>>4)*4+reg
    const int ci = (lane >> 4) * 4;
    const int cj = lane & 15;
    int isbf = 0;
    if constexpr (SCORES) isbf = flag[0];
    float ps[4] = {0.f, 0.f, 0.f, 0.f};
    float pr[4] = {0.f, 0.f, 0.f, 0.f};
    #pragma unroll
    for (int mt = 0; mt < 4; mt++) {
        #pragma unroll
        for (int rg = 0; rg < 4; rg++) {
            const int gi = i0 + wm + mt * 16 + ci + rg;
            if (gi >= mBound) continue;
            float bv = 0.f, rc = 1.f;
            if (BIAS_ROW) bv = (float)bias[gi];
            if (SCALE_ROW) {
                const float r_ = rsum[gi];
                rc = r_ > 0.f ? __builtin_amdgcn_rcpf(r_) : 0.f;
            }
            float vtv = 0.f, vrv = 0.f;
            if constexpr (SCORES) {
                if (gi < oBound) {
                    vtv = rdv(vtp, (size_t)(oBase + gi), isbf);
                    vrv = rdv(vrp, (size_t)(oBase + gi), isbf);
                }
            }
            #pragma unroll
            for (int nt = 0; nt < 4; nt++) {
                const int gj = j0 + wn + nt * 16 + cj;
                if (gj >= nBound) continue;
                float v = acc[mt][nt][rg];
                if (BIAS_ROW) { v += bv; v = v > 0.f ? v : 0.f; }
                if (SCALE_ROW) v *= rc;
                if constexpr (ATOMIC) {
                    atomicAdd((float*)&C[(size_t)gi * ldc + gj], v);
                } else {
                    C[(size_t)gi * ldc + gj] = (OutT)v;
                }
                if constexpr (SCORES) {
                    ps[nt] += v * vtv;
                    pr[nt] += v * vrv;
                }
            }
        }
    }
    if constexpr (SCORES) {
        #pragma unroll
        for (int nt = 0; nt < 4; nt++) {
            float p = ps[nt], r2 = pr[nt];
            p  += __shfl_down(p, 32);  p  += __shfl_down(p, 16);
            r2 += __shfl_down(r2, 32); r2 += __shfl_down(r2, 16);
            if (lane < 16) {
                const int gj = j0 + wn + nt * 16 + lane;
                if (gj < nBound) {
                    atomicAdd(&sAcc[gj], p);
                    atomicAdd(&rAcc[gj], r2);
                }
            }
        }
    }
}

// ---------------------------------------------------------------------------
// 64x64-tile gemm1 for small-M layers (CH<=512): 4 waves, each 32x32 (2x2
// fragments), BK=32, 16KB LDS -> many blocks/CU (latency-starved shapes).
// Always BIAS_ROW (relu+bias by row); optional fused SCORES. bf16 out.
// ---------------------------------------------------------------------------
template<bool SCORES>
__global__ __launch_bounds__(256, 4)
void gemm1_64(const bf16* __restrict__ A, int lda,
              const bf16* __restrict__ B, int ldb,
              const bf16* __restrict__ bias,
              bf16* __restrict__ C, int ldc,
              int K, int mBound, int nBound,
              const void* __restrict__ vtp, const void* __restrict__ vrp,
              const int* __restrict__ flag, int oBase, int oBound,
              float* __restrict__ sAcc, float* __restrict__ rAcc)
{
    __shared__ __align__(16) bf16 As[2][64 * 32];
    __shared__ __align__(16) bf16 Bs[2][64 * 32];
    const int tid  = threadIdx.x;
    const int wave = tid >> 6;
    const int lane = tid & 63;

    // bijective XCD swizzle (m204)
    const int nwg = gridDim.x * gridDim.y;
    const int orig = blockIdx.y * gridDim.x + blockIdx.x;
    const int q = nwg >> 3, rr = nwg & 7;
    const int xcd = orig & 7, idx = orig >> 3;
    const int swz = (xcd < rr ? xcd * (q + 1) : rr * (q + 1) + (xcd - rr) * q) + idx;
    const int i0 = (swz / gridDim.x) * 64;     // M (W rows)
    const int j0 = (swz % gridDim.x) * 64;     // N (H rows)

    // staging: wave w covers rows [w*16, w*16+16); lane -> (srow, 8-elem k)
    const int srow = lane >> 2;          // 0..15
    const int sk   = (lane & 3) * 8;
    const bf16* gA = A + (size_t)(i0 + wave * 16 + srow) * lda + sk;
    const bf16* gB = B + (size_t)(j0 + wave * 16 + srow) * ldb + sk;
    const int lo = wave * 16 * 32;

    const int wm = (wave >> 1) * 32;
    const int wn = (wave & 1) * 32;
    const int fr = lane & 15;
    const int fk = (lane >> 4) * 8;

    f32x4 acc[2][2] = {};

    auto stage = [&](int buf, int kt) {
        async_copy16(gA + kt, &As[buf][lo]);
        async_copy16(gB + kt, &Bs[buf][lo]);
    };

    stage(0, 0);
    __syncthreads();
    int cur = 0;

    for (int kt = 0; kt < K; kt += 32) {
        if (kt + 32 < K) stage(cur ^ 1, kt + 32);

        bf16x8 af[2], bfv[2];
        #pragma unroll
        for (int t = 0; t < 2; t++) {
            af[t]  = *(const bf16x8*)&As[cur][(wm + t * 16 + fr) * 32 + fk];
            bfv[t] = *(const bf16x8*)&Bs[cur][(wn + t * 16 + fr) * 32 + fk];
        }
        #pragma unroll
        for (int mt = 0; mt < 2; mt++)
            #pragma unroll
            for (int nt = 0; nt < 2; nt++)
                acc[mt][nt] = __builtin_amdgcn_mfma_f32_16x16x32_bf16(
                    af[mt], bfv[nt], acc[mt][nt], 0, 0, 0);

        __syncthreads();
        cur ^= 1;
    }

    const int ci = (lane >> 4) * 4;
    const int cj = lane & 15;
    int isbf = 0;
    if constexpr (SCORES) isbf = flag[0];
    float ps[2] = {0.f, 0.f};
    float pr[2] = {0.f, 0.f};
    #pragma unroll
    for (int mt = 0; mt < 2; mt++) {
        #pragma unroll
        for (int rg = 0; rg < 4; rg++) {
            const int gi = i0 + wm + mt * 16 + ci + rg;
            if (gi >= mBound) continue;
            const float bv = (float)bias[gi];
            float vtv = 0.f, vrv = 0.f;
            if constexpr (SCORES) {
                if (gi < oBound) {
                    vtv = rdv(vtp, (size_t)(oBase + gi), isbf);
                    vrv = rdv(vrp, (size_t)(oBase + gi), isbf);
                }
            }
            #pragma unroll
            for (int nt = 0; nt < 2; nt++) {
                const int gj = j0 + wn + nt * 16 + cj;
                if (gj >= nBound) continue;
                float v = acc[mt][nt][rg] + bv;
                v = v > 0.f ? v : 0.f;
                C[(size_t)gi * ldc + gj] = (bf16)v;
                if constexpr (SCORES) {
                    ps[nt] += v * vtv;
                    pr[nt] += v * vrv;
                }
            }
        }
    }
    if constexpr (SCORES) {
        #pragma unroll
        for (int nt = 0; nt < 2; nt++) {
            float p = ps[nt], r2 = pr[nt];
            p  += __shfl_down(p, 32);  p  += __shfl_down(p, 16);
            r2 += __shfl_down(r2, 32); r2 += __shfl_down(r2, 16);
            if (lane < 16) {
                const int gj = j0 + wn + nt * 16 + lane;
                if (gj < nBound) {
                    atomicAdd(&sAcc[gj], p);
                    atomicAdd(&rAcc[gj], r2);
                }
            }
        }
    }
}

// dst (rp x cp) bf16 = src (r x c, dual-mode) zero-padded
__global__ void padcopy(const void* __restrict__ src, int r, int c,
                        bf16* __restrict__ dst, int rp, int cp,
                        const int* __restrict__ flag)
{
    const int isbf = flag[0];
    long idx = (long)blockIdx.x * 256 + threadIdx.x;
    if (idx >= (long)rp * cp) return;
    int i = (int)(idx / cp), j = (int)(idx % cp);
    float v = 0.f;
    if (i < r && j < c) v = rdv(src, (size_t)i * c + j, isbf);
    dst[idx] = (bf16)v;
}

// fused multi-segment padcopy: 14 weight/bias segments in one grid-stride
// launch (replaces 14 tiny dispatches). Segment found by unrolled scan.
struct PadSeg { const void* src; bf16* dst; int r, c, cp; long base; };
struct PadArgs { PadSeg seg[14]; long total; };
__global__ void padcopy_multi(PadArgs a, const int* __restrict__ flag)
{
    const int isbf = flag[0];
    long idx = (long)blockIdx.x * 256 + threadIdx.x;
    const long str = (long)gridDim.x * 256;
    for (; idx < a.total; idx += str) {
        int s = 0;
        #pragma unroll
        for (int k = 1; k < 14; k++) if (idx >= a.seg[k].base) s = k;
        const long loc = idx - a.seg[s].base;
        const int cp = a.seg[s].cp;
        const int i = (int)(loc / cp), j = (int)(loc % cp);
        float v = 0.f;
        if (i < a.seg[s].r && j < a.seg[s].c)
            v = rdv(a.seg[s].src, (size_t)i * a.seg[s].c + j, isbf);
        a.seg[s].dst[loc] = (bf16)v;
    }
}

// XT (np x np bf16) = transpose of src (n x n, dual-mode), zero-padded.
__global__ void padcopy_T(const void* __restrict__ src, int n,
                          bf16* __restrict__ dst, int np,
                          const int* __restrict__ flag)
{
    __shared__ float t[32][33];
    const int isbf = flag[0];
    const int tx = threadIdx.x & 31;
    const int ty = threadIdx.x >> 5;     // 0..7
    const int i0 = blockIdx.y * 32;      // output row block (i = src col)
    const int k0 = blockIdx.x * 32;      // output col block (k = src row)
    #pragma unroll
    for (int q = 0; q < 4; q++) {        // stage src[k0+r][i0+tx]
        int k = k0 + ty + q * 8;
        float v = 0.f;
        if (k < n && i0 + tx < n) v = rdv(src, (size_t)k * n + i0 + tx, isbf);
        t[ty + q * 8][tx] = v;
    }
    __syncthreads();
    #pragma unroll
    for (int q = 0; q < 4; q++) {        // write dst[i0+r][k0+tx] = src[k0+tx][i0+r]
        int i = ty + q * 8;
        dst[(size_t)(i0 + i) * np + k0 + tx] = (bf16)t[tx][i];
    }
}

__global__ void zero_f32(float* __restrict__ p, int n)
{
    int i = blockIdx.x * 256 + threadIdx.x;
    if (i < n) p[i] = 0.f;
}

// grid-stride vectorized zero (n4 = count of float4)
__global__ void zero_f32v(f32x4* __restrict__ p, long n4)
{
    long i = (long)blockIdx.x * 256 + threadIdx.x;
    const long str = (long)gridDim.x * 256;
    const f32x4 z = {0.f, 0.f, 0.f, 0.f};
    for (; i < n4; i += str) p[i] = z;
}

// grid-stride f32 -> bf16 convert that re-zeroes the source as it goes
// (restores the "Hf is all-zero" invariant; kills one zero launch per layer)
__global__ void f32_to_bf16_zero(f32x4* __restrict__ src, bf16x4* __restrict__ dst, long n4)
{
    long i = (long)blockIdx.x * 256 + threadIdx.x;
    const long str = (long)gridDim.x * 256;
    const f32x4 z = {0.f, 0.f, 0.f, 0.f};
    for (; i < n4; i += str) {
        f32x4 v = src[i];
        src[i] = z;
        bf16x4 w;
        #pragma unroll
        for (int k = 0; k < 4; k++) w[k] = (__bf16)v[k];
        dst[i] = w;
    }
}

// ---------------------------------------------------------------------------
// Paired E-pass: block (bi<=bj) computes E tiles (I,J) and (J,I), 64x64 each.
// E[i,j] = exp(sigmoid(A[i,j]*(s[j]+vtb) + A[j,i]*(r[i]+vrb))), i,j<n else 0.
// CB=true: padded bf16 A (stride ldA), bf16 LDS [2][64][66] (16.9KB).
// CB=false: raw dual-mode A, f32 LDS [2][64][65].
// ---------------------------------------------------------------------------
template<bool CB>
__global__ __launch_bounds__(256)
void e_pass_pair(const void* __restrict__ A, int ldA, int n,
                 const float* __restrict__ s, const float* __restrict__ r,
                 const void* __restrict__ vtb, const void* __restrict__ vrb,
                 bf16* __restrict__ E, int ldE, float* __restrict__ rowsum,
                 const int* __restrict__ flag)
{
    extern __shared__ char smem[];
    const int bi = blockIdx.y, bj = blockIdx.x;
    if (bj < bi) return;
    const int isbf = flag[0];
    const int tid = threadIdx.x;
    const int i0 = bi * 64, j0 = bj * 64;
    const int tx = tid & 15;         // col group: 4 consecutive cols
    const int ty = tid >> 4;         // 0..15
    const int c0 = 4 * tx;
    const float bt = rdv(vtb, 0, isbf);
    const float br = rdv(vrb, 0, isbf);

    auto ld4 = [&](int row, int col) -> f32x4 {
        if constexpr (CB) return load4b((const bf16*)A, ldA, row, col);
        else              return load4g(A, n, row, col, isbf);
    };
    auto stT = [&](int which, int a, int b, float v) {
        if constexpr (CB) ((__bf16*)smem)[((which << 6) + a) * 66 + b] = (__bf16)v;
        else              ((float*)smem)[((which << 6) + a) * 65 + b] = v;
    };
    auto ldT = [&](int which, int a, int b) -> float {
        if constexpr (CB) return (float)((__bf16*)smem)[((which << 6) + a) * 66 + b];
        else              return ((float*)smem)[((which << 6) + a) * 65 + b];
    };

    #pragma unroll
    for (int rr = 0; rr < 4; rr++) {
        const int rw = ty + 16 * rr;                       // 0..63
        f32x4 v1 = ld4(i0 + rw, j0 + c0);                  // region1 row
        f32x4 v2 = ld4(j0 + rw, i0 + c0);                  // region2 row
        #pragma unroll
        for (int k = 0; k < 4; k++) {
            stT(0, c0 + k, rw, v1[k]);
            stT(1, c0 + k, rw, v2[k]);
        }
    }
    __syncthreads();

    const float LOG2E = 1.442695041f;

    // ---- tile1: rows I, cols J ----
    {
        f32x4 s4 = *(const f32x4*)&s[j0 + c0];
        #pragma unroll
        for (int k = 0; k < 4; k++) s4[k] += bt;
        #pragma unroll
        for (int q = 0; q < 4; q++) {
            const int li = ty + 16 * q;
            const int gi = i0 + li;
            const float rv = r[gi] + br;
            const f32x4 a = ld4(gi, j0 + c0);
            f32x4 ev;
            float part = 0.f;
            #pragma unroll
            for (int k = 0; k < 4; k++) {
                const float trn = ldT(1, li, c0 + k);          // A[gj][gi]
                const float x = a[k] * s4[k] + trn * rv;
                const float t = __builtin_amdgcn_exp2f(-x * LOG2E);
                const float sig = __builtin_amdgcn_rcpf(1.f + t);
                float e = __builtin_amdgcn_exp2f(sig * LOG2E);
                const int gj = j0 + c0 + k;
                e = (gi < n && gj < n) ? e : 0.f;
                ev[k] = e;
                part += e;
            }
            bf16x4 w;
            #pragma unroll
            for (int k = 0; k < 4; k++) w[k] = (__bf16)ev[k];
            *(bf16x4*)&E[(size_t)gi * ldE + j0 + c0] = w;
            part += __shfl_down(part, 8, 16);
            part += __shfl_down(part, 4, 16);
            part += __shfl_down(part, 2, 16);
            part += __shfl_down(part, 1, 16);
            if (tx == 0) atomicAdd(&rowsum[gi], part);
        }
    }

    // ---- tile2: rows J, cols I (skip on diagonal) ----
    if (bj > bi) {
        f32x4 s4 = *(const f32x4*)&s[i0 + c0];
        #pragma unroll
        for (int k = 0; k < 4; k++) s4[k] += bt;
        #pragma unroll
        for (int q = 0; q < 4; q++) {
            const int lr = ty + 16 * q;
            const int gr = j0 + lr;
            const float rv = r[gr] + br;
            const f32x4 a = ld4(gr, i0 + c0);
            f32x4 ev;
            float part = 0.f;
            #pragma unroll
            for (int k = 0; k < 4; k++) {
                const float trn = ldT(0, lr, c0 + k);          // A[gj][gr]
                const float x = a[k] * s4[k] + trn * rv;
                const float t = __builtin_amdgcn_exp2f(-x * LOG2E);
                const float sig = __builtin_amdgcn_rcpf(1.f + t);
                float e = __builtin_amdgcn_exp2f(sig * LOG2E);
                const int gj = i0 + c0 + k;
                e = (gr < n && gj < n) ? e : 0.f;
                ev[k] = e;
                part += e;
            }
            bf16x4 w;
            #pragma unroll
            for (int k = 0; k < 4; k++) w[k] = (__bf16)ev[k];
            *(bf16x4*)&E[(size_t)gr * ldE + i0 + c0] = w;
            part += __shfl_down(part, 8, 16);
            part += __shfl_down(part, 4, 16);
            part += __shfl_down(part, 2, 16);
            part += __shfl_down(part, 1, 16);
            if (tx == 0) atomicAdd(&rowsum[gr], part);
        }
    }
}

// D (MP x 128): rows m<G from gG[c,m] (dual); rows G..M-1 from H3[m-G,c]; else 0
__global__ void build_D(const void* __restrict__ gG, const bf16* __restrict__ H3,
                        bf16* __restrict__ D, const int* __restrict__ flag)
{
    const int isbf = flag[0];
    int idx = blockIdx.x * 256 + threadIdx.x;
    int m = idx >> 7, c = idx & 127;
    float v = 0.f;
    if (c < 64) {
        if (m < N_GENES)      v = rdv(gG, (size_t)c * N_GENES + m, isbf);
        else if (m < M_NODES) v = (float)H3[(size_t)(m - N_GENES) * 128 + c];
    }
    D[idx] = (bf16)v;
}

extern "C" void kernel_launch(void* const* d_in, const int* in_sizes, int n_in,
                              void* d_out, int out_size, void* d_ws, size_t ws_size,
                              hipStream_t stream)
{
    const void* X     = d_in[0];
    const void* A_enc = d_in[1];
    const void* A_dec = d_in[2];
    const void* gG    = d_in[3];
    const void *W[7], *Wb[7], *vt[7], *vtb[7], *vr[7], *vrb[7];
    for (int l = 0; l < 7; l++) {
        W[l]   = d_in[4 + 6 * l + 0];
        Wb[l]  = d_in[4 + 6 * l + 1];
        vt[l]  = d_in[4 + 6 * l + 2];
        vtb[l] = d_in[4 + 6 * l + 3];
        vr[l]  = d_in[4 + 6 * l + 4];
        vrb[l] = d_in[4 + 6 * l + 5];
    }

    const int fop[7] = {512, 256, 128, 256, 512, 4096, 1024};
    const int fip[7] = {3072, 512, 256, 128, 256, 512, 512};
    const int foR[7] = {512, 256, 64, 256, 512, 4000, 1000};
    const int fiR[7] = {3000, 512, 256, 64, 256, 512, 512};

    // gates: full-Z ZT (32 MB) at ws>=100 MB; bf16 A-cache (+32 MB) at >=130.
    const int  CHcap = (ws_size >= (size_t)100 * 1024 * 1024) ? 4096 : 1024;
    const bool useAB = (ws_size >= (size_t)130 * 1024 * 1024);

    // ---- workspace layout, small first ----
    char* ws = (char*)d_ws;
    size_t off = 0;
    auto alloc = [&](size_t bytes) -> void* {
        void* p = ws + off;
        off += (bytes + 255) & ~(size_t)255;
        return p;
    };
    int*   flag = (int*)alloc(256);
    float* sb   = (float*)alloc((size_t)MP * 4);   // sb, rb, rsum contiguous
    float* rb   = (float*)alloc((size_t)MP * 4);
    float* rsum = (float*)alloc((size_t)MP * 4);
    bf16* Bp[7];
    for (int l = 0; l < 7; l++) Bp[l] = (bf16*)alloc((size_t)fop[l] * 2);
    bf16* RA = (bf16*)alloc((size_t)NP * 512 * 2);   // H1 -> H3 -> D1
    bf16* RB = (bf16*)alloc((size_t)NP * 256 * 2);   // H2 -> Dd
    bf16* RC = (bf16*)alloc((size_t)MP * 512 * 2);   // D2
    bf16 *H1 = RA, *H3 = RA, *D1 = RA;
    bf16 *H2 = RB, *Dd = RB;
    bf16 *D2 = RC;
    bf16* Wp[7];
    for (int l = 0; l < 7; l++) Wp[l] = (bf16*)alloc((size_t)fop[l] * fip[l] * 2);
    float* Hf = (float*)alloc((size_t)MP * 512 * 4);        // 8 MB split-K f32 accum
    bf16*  ZT = (bf16*)alloc((size_t)CHcap * MP * 2);       // 8 or 32 MB
    bf16*  E  = (bf16*)alloc((size_t)MP * MP * 2);          // 32 MB
    bf16*  Ab = useAB ? (bf16*)alloc((size_t)MP * MP * 2) : nullptr;  // 32 MB A-cache
    // XT = pad(X^T) bf16 aliases E: consumed by layer-0 gemm1 before e_pass.
    bf16* XT = E;

    // split-K slices for contraction Kc: only for starved grids (base<192);
    // smallest S dividing the step count with slice>=256 and grid>=384
    // (capped 1536) — halves the atomic-write tax vs the old >=768 target.
    auto pickS = [](int base, int Kc) -> int {
        if (base >= 192) return 1;
        const int steps = Kc / 32;
        int best = 1;
        for (int S = 1; S <= 16; S++) {
            if (steps % S) continue;
            if (Kc / S < 256) continue;
            if (base * S > 1536) break;
            best = S;
            if (base * S >= 384) break;
        }
        return best;
    };

    // ---- prep ----
    sniff_dtype<<<1, 256, 0, stream>>>((const unsigned int*)X, flag);
    {
        PadArgs pa;
        long base = 0;
        for (int l = 0; l < 7; l++) {
            pa.seg[l] = {W[l], Wp[l], foR[l], fiR[l], fip[l], base};
            base += (long)fop[l] * fip[l];
        }
        for (int l = 0; l < 7; l++) {
            pa.seg[7 + l] = {Wb[l], Bp[l], 1, foR[l], fop[l], base};
            base += fop[l];
        }
        pa.total = base;
        padcopy_multi<<<2048, 256, 0, stream>>>(pa, flag);
    }
    padcopy_T<<<dim3(NP / 32, NP / 32), 256, 0, stream>>>(X, N_CELLS, XT, NP, flag);
    zero_f32v<<<2048, 256, 0, stream>>>((f32x4*)Hf, (long)MP * 512);   // once; convert re-zeroes
    if (useAB)   // encoder-phase A cache (NP x NP bf16)
        padcopy<<<dim3((NP * NP) / 256), 256, 0, stream>>>(
            A_enc, N_CELLS, N_CELLS, Ab, NP, NP, flag);

    const unsigned smemCB = 2 * 64 * 66 * 2;        // bf16 path
    const unsigned smemF  = 2 * 64 * 65 * 4;        // f32 fallback

    auto layer = [&](const bf16* Hin, int l, const void* Araw, int nABpad,
                     int nReal, int nPad, bf16* HoutB, float* HoutF,
                     int ldOut, int mB, int nBtot) {
        const int K = fip[l], NO = fop[l];
        const int CH = NO > CHcap ? CHcap : NO;
        const int nch = NO / CH;
        // gemm1 (operand-swapped): ZT[o,i] = relu(sum_k W[o,k]*Hin[i,k]+b[o]).
        // CH<=512 -> 64^2 tile (4x the blocks on latency-starved shapes).
        auto gemm1 = [&](int c, bool withScores) {
            int sB = foR[l] - c * CH;
            if (sB > CH) sB = CH;
            if (sB < 0) sB = 0;
            const bf16* Aw = Wp[l] + (size_t)c * CH * K;
            if (CH <= 512) {
                if (withScores)
                    gemm1_64<true><<<dim3(nPad / 64, CH / 64), 256, 0, stream>>>(
                        Aw, K, Hin, K, Bp[l] + c * CH, ZT, nPad, K, CH, nPad,
                        vt[l], vr[l], flag, c * CH, sB, sb, rb);
                else
                    gemm1_64<false><<<dim3(nPad / 64, CH / 64), 256, 0, stream>>>(
                        Aw, K, Hin, K, Bp[l] + c * CH, ZT, nPad, K, CH, nPad,
                        nullptr, nullptr, nullptr, 0, 0, nullptr, nullptr);
            } else {
                if (withScores)
                    gemm_nt<true, false, false, true, bf16><<<dim3(nPad / 128, CH / 128), 256, 0, stream>>>(
                        Aw, K, Hin, K, Bp[l] + c * CH, nullptr,
                        ZT, nPad, K, CH, nPad,
                        vt[l], vr[l], flag, c * CH, sB, sb, rb);
                else
                    gemm_nt<true, false, false, false, bf16><<<dim3(nPad / 128, CH / 128), 256, 0, stream>>>(
                        Aw, K, Hin, K, Bp[l] + c * CH, nullptr,
                        ZT, nPad, K, CH, nPad,
                        nullptr, nullptr, nullptr, 0, 0, nullptr, nullptr);
            }
        };
        // pass A: zero scores (sb, rb, rsum contiguous) then gemm1+scores
        zero_f32<<<dim3(3 * MP / 256), 256, 0, stream>>>(sb, 3 * MP);
        for (int c = 0; c < nch; c++) gemm1(c, true);
        // full E + row sums (score biases folded in)
        if (useAB)
            e_pass_pair<true><<<dim3(nPad / 64, nPad / 64), 256, smemCB, stream>>>(
                Ab, nABpad, nReal, sb, rb, vtb[l], vrb[l], E, nPad, rsum, flag);
        else
            e_pass_pair<false><<<dim3(nPad / 64, nPad / 64), 256, smemF, stream>>>(
                Araw, nReal, nReal, sb, rb, vtb[l], vrb[l], E, nPad, rsum, flag);
        // pass B: gemm2 (contraction = nPad E-columns), softmax scale folded
        // in via rcp(rsum). Hf is pre-zeroed (invariant kept by convert).
        for (int c = 0; c < nch; c++) {
            if (nch > 1) gemm1(c, false);   // ZT intact when nch==1
            int colBase = c * CH;
            int nB = nBtot - colBase;
            if (nB > CH) nB = CH;
            if (nB <= 0) continue;
            const int bx = CH / 128, by = nPad / 128;
            if (HoutB) {
                const int S = pickS(bx * by, nPad);
                gemm_nt<false, true, true, false, float><<<dim3(bx, by, S), 256, 0, stream>>>(
                    E, nPad, ZT, nPad, nullptr, rsum,
                    Hf + colBase, nBtot, nPad, nPad, nB,
                    nullptr, nullptr, nullptr, 0, 0, nullptr, nullptr);
            } else {
                const int S = (nch == 1 && bx * by == 256) ? 2 : 1;
                if (S == 2) {
                    zero_f32v<<<2048, 256, 0, stream>>>(
                        (f32x4*)HoutF, (long)mB * ldOut / 4);
                    gemm_nt<false, true, true, false, float><<<dim3(bx, by, S), 256, 0, stream>>>(
                        E, nPad, ZT, nPad, nullptr, rsum,
                        HoutF + colBase, ldOut, nPad, mB, nB,
                        nullptr, nullptr, nullptr, 0, 0, nullptr, nullptr);
                } else {
                    gemm_nt<false, true, false, false, float><<<dim3(bx, by), 256, 0, stream>>>(
                        E, nPad, ZT, nPad, nullptr, rsum,
                        HoutF + colBase, ldOut, nPad, mB, nB,
                        nullptr, nullptr, nullptr, 0, 0, nullptr, nullptr);
                }
            }
        }
        if (HoutB)
            f32_to_bf16_zero<<<2048, 256, 0, stream>>>(
                (f32x4*)Hf, (bf16x4*)HoutB, (long)nPad * nBtot / 4);
    };

    // encoder (H0 = X^T staged as XT by padcopy_T)
    layer(XT,      0, A_enc, NP, N_CELLS, NP, H1, nullptr, 512, NP, 512);
    layer(H1,      1, A_enc, NP, N_CELLS, NP, H2, nullptr, 256, NP, 256);
    layer(H2,      2, A_enc, NP, N_CELLS, NP, H3, nullptr, 128, NP, 128);
    // decoder input D = concat([gG, H3^T], axis=1)^T
    build_D<<<dim3((MP * 128) / 256), 256, 0, stream>>>(gG, H3, Dd, flag);
    if (useAB)   // decoder-phase A cache (MP x MP bf16, overwrites enc cache)
        padcopy<<<dim3((int)(((long)MP * MP) / 256)), 256, 0, stream>>>(
            A_dec, M_NODES, M_NODES, Ab, MP, MP, flag);
    layer(Dd, 3, A_dec, MP, M_NODES, MP, D1, nullptr, 256, MP, 256);
    layer(D1, 4, A_dec, MP, M_NODES, MP, D2, nullptr, 512, MP, 512);
    // outputs are float32 (reference dtype)
    float* outCell = (float*)d_out;
    float* outGene = outCell + (size_t)M_NODES * M_NODES;
    layer(D2, 5, A_dec, MP, M_NODES, MP, nullptr, outCell, 4000, 4000, 4000);
    layer(D2, 6, A_dec, MP, M_NODES, MP, nullptr, outGene, 1000, 4000, 1000);
}